// Round 5
// baseline (79160.999 us; speedup 1.0000x reference)
//
#include <hip/hip_runtime.h>
#include <hip/hip_cooperative_groups.h>

namespace cg = cooperative_groups;

#define NPTS 8192
#define N2 (NPTS * 2)
#define TPB 512
#define NBLK 256           // 1 block per CU, co-resident (cooperative)
#define IPB 32             // i-rows owned per block
#define NSLICE 16          // j-slices (TPB/IPB)
#define JCH 1024           // j chunk staged in LDS
#define NJCH (NPTS / JCH)  // 8
#define JPT (JCH / NSLICE) // 64 inner j per slice per chunk
#define T_ITERS 1408
#define NUG 1.0e-4
#define LAM 1.0e-5

#if __has_builtin(__builtin_amdgcn_exp2f)
#define EXP2F(x) __builtin_amdgcn_exp2f(x)
#else
#define EXP2F(x) __expf(0.6931471805599453f * (x))
#endif

// ---------------- setup ----------------
// u = x / sqrt(2 ln2)  =>  K_ij = 2^(-(|u_i|^2 + |u_j|^2 - 2 u_i.u_j))
extern "C" __global__ void __launch_bounds__(TPB)
k_setup(const float* __restrict__ Xmu, const float* __restrict__ Yeta,
        const float* __restrict__ Ymu, const float* __restrict__ Z,
        float4* __restrict__ U4, float4* __restrict__ W4, float* __restrict__ NS,
        float4* __restrict__ M4, float4* __restrict__ Y4,
        float4* __restrict__ SA1, float4* __restrict__ SB0, float4* __restrict__ SB1,
        double* __restrict__ rrsetup)
{
  const float c2 = 0.84932180028802f;        // 1/sqrt(2 ln 2)
  int tid = threadIdx.x;
  int idx = blockIdx.x * TPB + tid;          // 0..16383
  int i = idx >> 1;
  float z = Z[idx];
  if ((idx & 1) == 0) {
    float a0 = Xmu[2 * i], a1 = Xmu[2 * i + 1];
    float e0 = Yeta[2 * i], e1 = Yeta[2 * i + 1];
    float m0 = Ymu[2 * i], m1 = Ymu[2 * i + 1];
    float z0 = Z[2 * i], z1 = Z[2 * i + 1];
    float u0 = c2 * a0, u1 = c2 * a1, u2 = c2 * e0, u3 = c2 * e1;
    float n = fmaf(u3, u3, fmaf(u2, u2, fmaf(u1, u1, u0 * u0)));
    U4[i] = make_float4(u0, u1, u2, u3);
    W4[i] = make_float4(2.f * u0, 2.f * u1, 2.f * u2, 2.f * u3);
    NS[i] = n;
    M4[i] = make_float4(a0, a1, e0 + z0, e1 + z1);
    Y4[i] = make_float4(a0, a1, m0, m1);
    SA1[i] = make_float4(z0, z1, 0.f, 0.f);  // (r0,r1,p0,p1) for t=0
    SB0[i] = make_float4(0.f, 0.f, n, 0.f);  // (q0,q1,n,-) both slots carry n
    SB1[i] = make_float4(0.f, 0.f, n, 0.f);
  }
  __shared__ double sd[TPB];
  sd[tid] = (double)z * (double)z;
  __syncthreads();
  for (int st = TPB >> 1; st >= 2; st >>= 1) {
    if (tid < st) sd[tid] += sd[tid + st];
    __syncthreads();
  }
  if (tid < 2) rrsetup[blockIdx.x * 2 + tid] = sd[tid];  // 32 blocks x 2
}

// ---------------- MMD: three fused Gram sums ----------------
#define MTPB 256
#define MCH 1024
extern "C" __global__ void __launch_bounds__(MTPB)
k_mmd(const float4* __restrict__ M4, const float4* __restrict__ Y4,
      double* __restrict__ mmdpart)
{
  __shared__ float4 sM[MCH];
  __shared__ float4 sY[MCH];
  __shared__ double sred[MTPB];
  int tid = threadIdx.x;
  int blk = blockIdx.x;            // 256 = 32 itiles x 8 chunks
  int itile = blk >> 3;
  int ch = blk & 7;
  int j0 = ch * MCH;
  for (int u = tid; u < MCH; u += MTPB) {
    sM[u] = M4[j0 + u];
    sY[u] = Y4[j0 + u];
  }
  __syncthreads();
  int i = itile * MTPB + tid;
  float4 mi = M4[i];
  float4 yi = Y4[i];
  double szz = 0.0, szy = 0.0, syy = 0.0;
  for (int jj = 0; jj < MCH; ++jj) {
    float4 mj = sM[jj];
    float4 yj = sY[jj];
    float d0 = mi.x - mj.x, d1 = mi.y - mj.y;
    float a = fmaf(d1, d1, d0 * d0);
    float u0 = mi.z - mj.z, u1 = mi.w - mj.w;
    float v0 = mi.z - yj.z, v1 = mi.w - yj.w;
    float w0 = yi.z - yj.z, w1 = yi.w - yj.w;
    float dzz = fmaf(u0, u0, fmaf(u1, u1, a));
    float dzy = fmaf(v0, v0, fmaf(v1, v1, a));
    float dyy = fmaf(w0, w0, fmaf(w1, w1, a));
    szz += (double)__expf(-0.5f * dzz);
    szy += (double)__expf(-0.5f * dzy);
    syy += (double)__expf(-0.5f * dyy);
  }
  double v[3] = {szz, szy, syy};
  for (int k = 0; k < 3; ++k) {
    sred[tid] = v[k];
    __syncthreads();
    for (int st = MTPB >> 1; st >= 1; st >>= 1) {
      if (tid < st) sred[tid] += sred[tid + st];
      __syncthreads();
    }
    if (tid == 0) mmdpart[blk * 3 + k] = sred[0];
    __syncthreads();
  }
}

// ---------------- persistent CG: all iterations, 1 grid.sync each ----------------
extern "C" __global__ void __launch_bounds__(TPB, 1)
k_cg_persist(const float4* __restrict__ U4, const float4* __restrict__ W4,
             const float* __restrict__ NS, const float* __restrict__ Z,
             float4* __restrict__ SA0, float4* __restrict__ SA1,
             float4* __restrict__ SB0, float4* __restrict__ SB1,
             double* __restrict__ xout, double* __restrict__ pout,
             double* __restrict__ part0, double* __restrict__ part1,
             double* __restrict__ rho0, double* __restrict__ rho1,
             const double* __restrict__ rrsetup)
{
  cg::grid_group grid = cg::this_grid();
  __shared__ float4 sw[2][JCH];              // 2u_j (double-buffered)
  __shared__ float4 sa[2][JCH];              // (n_j, pn0, pn1, -)
  __shared__ float qred[NSLICE][IPB][2];
  __shared__ double s1[TPB], s2[TPB], s3[TPB];
  __shared__ double sc[4];                   // a0,a1,b0,b1

  int tid = threadIdx.x;
  int blk = blockIdx.x;
  int il = tid & (IPB - 1);
  int slice = tid >> 5;
  int irow = blk * IPB + il;
  float4 ui = U4[irow];
  float ni = NS[irow];

  // owned CG state in registers: tid < 64 owns (i = blk*32 + tid/2, col = tid&1)
  int oidx = blk * 64 + tid;                 // valid for tid<64
  double r_o = 0.0, p_o = 0.0, q_o = 0.0, x_o = 0.0;
  if (tid < 64) r_o = (double)Z[oidx];

  for (int t = 0; t < T_ITERS; ++t) {
    const float4* SAr = (t & 1) ? SA0 : SA1;
    const float4* SBr = (t & 1) ? SB0 : SB1;
    float4* SAw = (t & 1) ? SA1 : SA0;
    float4* SBw = (t & 1) ? SB1 : SB0;
    const double* partr = (t & 1) ? part0 : part1;
    double* partw = (t & 1) ? part1 : part0;
    const double* rhor = (t & 1) ? rho0 : rho1;
    double* rhow = (t & 1) ? rho1 : rho0;

    // ---- scalar phase (redundant per block, deterministic) ----
    if (t == 0) {
      s1[tid] = (tid < 64) ? rrsetup[tid] : 0.0;
      __syncthreads();
      for (int st = 32; st >= 2; st >>= 1) {
        if (tid < st) s1[tid] += s1[tid + st];
        __syncthreads();
      }
      if (tid < 2) { rhow[tid] = s1[tid]; sc[tid] = 0.0; sc[2 + tid] = 0.0; }
      __syncthreads();
    } else {
      s1[tid] = partr[tid];
      s2[tid] = partr[512 + tid];
      s3[tid] = partr[1024 + tid];
      __syncthreads();
      for (int st = 256; st >= 2; st >>= 1) {
        if (tid < st) {
          s1[tid] += s1[tid + st];
          s2[tid] += s2[tid + st];
          s3[tid] += s3[tid + st];
        }
        __syncthreads();
      }
      if (tid < 2) {
        double rho_o = rhor[tid];
        double al = rho_o / s1[tid];
        double rho_n = fma(al, fma(al, s3[tid], -2.0 * s2[tid]), rho_o);
        rhow[tid] = rho_n;
        sc[tid] = al;
        sc[2 + tid] = rho_n / rho_o;
      }
      __syncthreads();
    }
    double da0 = sc[0], da1 = sc[1], db0 = sc[2], db1 = sc[3];
    float a0 = (float)da0, a1 = (float)da1, b0 = (float)db0, b1 = (float)db1;

    // ---- matvec over all j, double-buffered chunks ----
    float4 w_r[2], sa_r[2];
#define LOADC(c) { int base = (c) * JCH;                                   \
      _Pragma("unroll")                                                     \
      for (int k = 0; k < 2; ++k) {                                         \
        int j = base + tid + k * TPB;                                       \
        w_r[k] = W4[j];                                                     \
        float4 s = SAr[j];                                                  \
        float4 qv = SBr[j];                                                 \
        float pn0 = fmaf(b0, s.z, fmaf(-a0, qv.x, s.x));                    \
        float pn1 = fmaf(b1, s.w, fmaf(-a1, qv.y, s.y));                    \
        sa_r[k] = make_float4(qv.z, pn0, pn1, 0.f);                         \
      } }
#define WRITEC(buf) { _Pragma("unroll")                                     \
      for (int k = 0; k < 2; ++k) {                                         \
        int u = tid + k * TPB;                                              \
        sw[buf][u] = w_r[k];                                                \
        sa[buf][u] = sa_r[k];                                               \
      } }
    float qa0 = 0.f, qa1 = 0.f;
    LOADC(0);
    WRITEC(0);
    for (int c = 0; c < NJCH; ++c) {
      if (c + 1 < NJCH) LOADC(c + 1);
      __syncthreads();                       // buf[c&1] writes visible
      int bsel = c & 1;
      int jlo = slice * JPT;
#pragma unroll 4
      for (int jj = 0; jj < JPT; ++jj) {
        float4 w = sw[bsel][jlo + jj];
        float4 aa = sa[bsel][jlo + jj];
        float ttn = -(ni + aa.x);
        ttn = fmaf(ui.x, w.x, ttn);
        ttn = fmaf(ui.y, w.y, ttn);
        ttn = fmaf(ui.z, w.z, ttn);
        ttn = fmaf(ui.w, w.w, ttn);
        float e = EXP2F(ttn);
        qa0 = fmaf(e, aa.y, qa0);
        qa1 = fmaf(e, aa.z, qa1);
      }
      if (c + 1 < NJCH) WRITEC((c + 1) & 1); // other buffer: race-free
    }
    qred[slice][il][0] = qa0;
    qred[slice][il][1] = qa1;
    __syncthreads();

    // ---- epilogue: owned rows, f64 recurrence in registers ----
    double pqv = 0.0, rqv = 0.0, qqv = 0.0;
    if (tid < 64) {
      int io = tid >> 1, col = tid & 1;
      double qg = 0.0;
#pragma unroll
      for (int s = 0; s < NSLICE; ++s) qg += (double)qred[s][io][col];
      double al = col ? da1 : da0;
      double be = col ? db1 : db0;
      double rn = fma(-al, q_o, r_o);
      double pn = fma(be, p_o, rn);
      double xn = fma(al, p_o, x_o);
      double qn = fma((double)NUG, pn, qg);
      r_o = rn; p_o = pn; q_o = qn; x_o = xn;
      int i = blk * IPB + io;
      float* SAf = (float*)SAw;
      float* SBf = (float*)SBw;
      SAf[i * 4 + col] = (float)rn;          // r0,r1
      SAf[i * 4 + 2 + col] = (float)pn;      // p0,p1
      SBf[i * 4 + col] = (float)qn;          // q0,q1 (comp 2 = n, untouched)
      pqv = pn * qn;
      rqv = rn * qn;
      qqv = qn * qn;
    }
    s1[tid] = pqv; s2[tid] = rqv; s3[tid] = qqv;
    __syncthreads();
    for (int st = 32; st >= 2; st >>= 1) {
      if (tid < st) {
        s1[tid] += s1[tid + st];
        s2[tid] += s2[tid + st];
        s3[tid] += s3[tid + st];
      }
      __syncthreads();
    }
    if (tid < 2) {
      partw[blk * 2 + tid] = s1[tid];
      partw[512 + blk * 2 + tid] = s2[tid];
      partw[1024 + blk * 2 + tid] = s3[tid];
    }
    grid.sync();
  }
  if (tid < 64) {
    xout[oidx] = x_o;
    pout[oidx] = p_o;
  }
#undef LOADC
#undef WRITEC
}

// ---------------- final: last x half-step + combine ----------------
extern "C" __global__ void __launch_bounds__(TPB)
k_final(const float* __restrict__ Z, const double* __restrict__ x,
        const double* __restrict__ plast, const double* __restrict__ part_last,
        const double* __restrict__ rho_last, const double* __restrict__ mmdpart,
        float* __restrict__ out)
{
  __shared__ double s1[TPB];
  __shared__ double sc2[2];
  int tid = threadIdx.x;
  s1[tid] = part_last[tid];
  __syncthreads();
  for (int st = 256; st >= 2; st >>= 1) {
    if (tid < st) s1[tid] += s1[tid + st];
    __syncthreads();
  }
  if (tid < 2) sc2[tid] = rho_last[tid] / s1[tid];
  __syncthreads();
  double al = sc2[tid & 1];
  double zx = 0.0;
  for (int idx = tid; idx < N2; idx += TPB)   // stride even: parity fixed
    zx += (double)Z[idx] * fma(al, plast[idx], x[idx]);
  double ZX, S0, S1v, S2v;
  s1[tid] = zx;
  __syncthreads();
  for (int st = 256; st >= 1; st >>= 1) { if (tid < st) s1[tid] += s1[tid + st]; __syncthreads(); }
  ZX = s1[0]; __syncthreads();
  s1[tid] = (tid < 256) ? mmdpart[tid * 3 + 0] : 0.0;
  __syncthreads();
  for (int st = 256; st >= 1; st >>= 1) { if (tid < st) s1[tid] += s1[tid + st]; __syncthreads(); }
  S0 = s1[0]; __syncthreads();
  s1[tid] = (tid < 256) ? mmdpart[tid * 3 + 1] : 0.0;
  __syncthreads();
  for (int st = 256; st >= 1; st >>= 1) { if (tid < st) s1[tid] += s1[tid + st]; __syncthreads(); }
  S1v = s1[0]; __syncthreads();
  s1[tid] = (tid < 256) ? mmdpart[tid * 3 + 2] : 0.0;
  __syncthreads();
  for (int st = 256; st >= 1; st >>= 1) { if (tid < st) s1[tid] += s1[tid + st]; __syncthreads(); }
  S2v = s1[0];
  if (tid == 0) {
    double nn = (double)NPTS * (double)NPTS;
    double mmd = (S0 - 2.0 * S1v + S2v) / nn;
    out[0] = (float)(mmd + LAM * ZX);
  }
}

extern "C" void kernel_launch(void* const* d_in, const int* in_sizes, int n_in,
                              void* d_out, int out_size, void* d_ws, size_t ws_size,
                              hipStream_t stream)
{
  (void)in_sizes; (void)n_in; (void)out_size; (void)ws_size;
  const float* Xmu  = (const float*)d_in[0];
  const float* Yeta = (const float*)d_in[1];
  const float* Ymu  = (const float*)d_in[2];
  const float* Z    = (const float*)d_in[3];
  float* out = (float*)d_out;

  char* w = (char*)d_ws;
  float4* U4      = (float4*)(w);                      // 128K
  float4* W4      = (float4*)(w + (128 << 10));        // 128K
  float*  NS      = (float*)(w + (256 << 10));         // 32K
  float4* M4      = (float4*)(w + (288 << 10));        // 128K
  float4* Y4      = (float4*)(w + (416 << 10));        // 128K
  float4* SA0     = (float4*)(w + (544 << 10));        // 128K
  float4* SA1     = (float4*)(w + (672 << 10));        // 128K
  float4* SB0     = (float4*)(w + (800 << 10));        // 128K
  float4* SB1     = (float4*)(w + (928 << 10));        // 128K
  double* xout    = (double*)(w + (1056 << 10));       // 128K
  double* pout    = (double*)(w + (1184 << 10));       // 128K
  double* part0   = (double*)(w + (1312 << 10));       // 12.3K
  double* part1   = (double*)(w + (1328 << 10));       // 12.3K
  double* rho0    = (double*)(w + (1344 << 10));
  double* rho1    = (double*)(w + (1344 << 10) + 64);
  double* rrsetup = (double*)(w + (1345 << 10));       // 512B
  double* mmdpart = (double*)(w + (1346 << 10));       // 6K

  hipLaunchKernelGGL(k_setup, dim3(N2 / TPB), dim3(TPB), 0, stream,
                     Xmu, Yeta, Ymu, Z, U4, W4, NS, M4, Y4, SA1, SB0, SB1, rrsetup);
  hipLaunchKernelGGL(k_mmd, dim3(256), dim3(MTPB), 0, stream, M4, Y4, mmdpart);

  {
    const float4* a0 = U4; const float4* a1 = W4;
    const float* a2 = NS; const float* a3 = Z;
    float4* a4 = SA0; float4* a5 = SA1; float4* a6 = SB0; float4* a7 = SB1;
    double* a8 = xout; double* a9 = pout;
    double* a10 = part0; double* a11 = part1;
    double* a12 = rho0; double* a13 = rho1;
    const double* a14 = rrsetup;
    void* args[] = {&a0, &a1, &a2, &a3, &a4, &a5, &a6, &a7,
                    &a8, &a9, &a10, &a11, &a12, &a13, &a14};
    hipLaunchCooperativeKernel((void*)k_cg_persist, dim3(NBLK), dim3(TPB),
                               args, 0, stream);
  }

  int last = (T_ITERS - 1) & 1;   // = 1
  hipLaunchKernelGGL(k_final, dim3(1), dim3(TPB), 0, stream,
                     Z, xout, pout, last ? part1 : part0,
                     last ? rho1 : rho0, mmdpart, out);
}

// Round 6
// 73427.490 us; speedup vs baseline: 1.0781x; 1.0781x over previous
//
#include <hip/hip_runtime.h>
#include <hip/hip_cooperative_groups.h>

namespace cg = cooperative_groups;

#define NPTS 8192
#define N2 (NPTS * 2)
#define TPB 512
#define NBLK 256           // 1 block per CU, co-resident (cooperative)
#define IPB 32             // i-rows owned per block
#define IB 8               // i-rows per thread (register-blocked)
#define NIG (IPB / IB)     // 4 i-groups
#define NJS 128            // j-slices (TPB / NIG)
#define JCH 1024           // j chunk staged in LDS
#define NJCH (NPTS / JCH)  // 8
#define JPTC (JCH / NJS)   // 8 j per thread per chunk
#define T_ITERS 1408
#define NUG 1.0e-4
#define LAM 1.0e-5

#if __has_builtin(__builtin_amdgcn_exp2f)
#define EXP2F(x) __builtin_amdgcn_exp2f(x)
#else
#define EXP2F(x) __expf(0.6931471805599453f * (x))
#endif

// ---------------- setup ----------------
// u = x / sqrt(2 ln2)  =>  K_ij = 2^(-(|u_i|^2 + |u_j|^2 - 2 u_i.u_j))
extern "C" __global__ void __launch_bounds__(TPB)
k_setup(const float* __restrict__ Xmu, const float* __restrict__ Yeta,
        const float* __restrict__ Ymu, const float* __restrict__ Z,
        float4* __restrict__ U4, float4* __restrict__ W4, float* __restrict__ NS,
        float4* __restrict__ M4, float4* __restrict__ Y4,
        float4* __restrict__ SA1, float4* __restrict__ SB0, float4* __restrict__ SB1,
        double* __restrict__ rrsetup)
{
  const float c2 = 0.84932180028802f;        // 1/sqrt(2 ln 2)
  int tid = threadIdx.x;
  int idx = blockIdx.x * TPB + tid;          // 0..16383
  int i = idx >> 1;
  float z = Z[idx];
  if ((idx & 1) == 0) {
    float a0 = Xmu[2 * i], a1 = Xmu[2 * i + 1];
    float e0 = Yeta[2 * i], e1 = Yeta[2 * i + 1];
    float m0 = Ymu[2 * i], m1 = Ymu[2 * i + 1];
    float z0 = Z[2 * i], z1 = Z[2 * i + 1];
    float u0 = c2 * a0, u1 = c2 * a1, u2 = c2 * e0, u3 = c2 * e1;
    float n = fmaf(u3, u3, fmaf(u2, u2, fmaf(u1, u1, u0 * u0)));
    U4[i] = make_float4(u0, u1, u2, u3);
    W4[i] = make_float4(2.f * u0, 2.f * u1, 2.f * u2, 2.f * u3);
    NS[i] = n;
    M4[i] = make_float4(a0, a1, e0 + z0, e1 + z1);
    Y4[i] = make_float4(a0, a1, m0, m1);
    SA1[i] = make_float4(z0, z1, 0.f, 0.f);  // (r0,r1,p0,p1) for t=0
    SB0[i] = make_float4(0.f, 0.f, n, 0.f);  // (q0,q1,n,-) both slots carry n
    SB1[i] = make_float4(0.f, 0.f, n, 0.f);
  }
  __shared__ double sd[TPB];
  sd[tid] = (double)z * (double)z;
  __syncthreads();
  for (int st = TPB >> 1; st >= 2; st >>= 1) {
    if (tid < st) sd[tid] += sd[tid + st];
    __syncthreads();
  }
  if (tid < 2) rrsetup[blockIdx.x * 2 + tid] = sd[tid];  // 32 blocks x 2
}

// ---------------- MMD: three fused Gram sums ----------------
#define MTPB 256
#define MCH 1024
extern "C" __global__ void __launch_bounds__(MTPB)
k_mmd(const float4* __restrict__ M4, const float4* __restrict__ Y4,
      double* __restrict__ mmdpart)
{
  __shared__ float4 sM[MCH];
  __shared__ float4 sY[MCH];
  __shared__ double sred[MTPB];
  int tid = threadIdx.x;
  int blk = blockIdx.x;            // 256 = 32 itiles x 8 chunks
  int itile = blk >> 3;
  int ch = blk & 7;
  int j0 = ch * MCH;
  for (int u = tid; u < MCH; u += MTPB) {
    sM[u] = M4[j0 + u];
    sY[u] = Y4[j0 + u];
  }
  __syncthreads();
  int i = itile * MTPB + tid;
  float4 mi = M4[i];
  float4 yi = Y4[i];
  double szz = 0.0, szy = 0.0, syy = 0.0;
  for (int jj = 0; jj < MCH; ++jj) {
    float4 mj = sM[jj];
    float4 yj = sY[jj];
    float d0 = mi.x - mj.x, d1 = mi.y - mj.y;
    float a = fmaf(d1, d1, d0 * d0);
    float u0 = mi.z - mj.z, u1 = mi.w - mj.w;
    float v0 = mi.z - yj.z, v1 = mi.w - yj.w;
    float w0 = yi.z - yj.z, w1 = yi.w - yj.w;
    float dzz = fmaf(u0, u0, fmaf(u1, u1, a));
    float dzy = fmaf(v0, v0, fmaf(v1, v1, a));
    float dyy = fmaf(w0, w0, fmaf(w1, w1, a));
    szz += (double)__expf(-0.5f * dzz);
    szy += (double)__expf(-0.5f * dzy);
    syy += (double)__expf(-0.5f * dyy);
  }
  double v[3] = {szz, szy, syy};
  for (int k = 0; k < 3; ++k) {
    sred[tid] = v[k];
    __syncthreads();
    for (int st = MTPB >> 1; st >= 1; st >>= 1) {
      if (tid < st) sred[tid] += sred[tid + st];
      __syncthreads();
    }
    if (tid == 0) mmdpart[blk * 3 + k] = sred[0];
    __syncthreads();
  }
}

// ---------------- persistent CG: all iterations, 1 grid.sync each ----------------
// Thread decomposition: ig = tid>>7 owns 8 i-rows (regs); js = tid&127 j-slice.
// Per LDS (w_j, a_j) read -> 8 pair updates: 4 B LDS per pair.
extern "C" __global__ void __launch_bounds__(TPB, 1)
k_cg_persist(const float4* __restrict__ U4, const float4* __restrict__ W4,
             const float* __restrict__ NS, const float* __restrict__ Z,
             float4* __restrict__ SA0, float4* __restrict__ SA1,
             float4* __restrict__ SB0, float4* __restrict__ SB1,
             double* __restrict__ xout, double* __restrict__ pout,
             double* __restrict__ part0, double* __restrict__ part1,
             double* __restrict__ rho0, double* __restrict__ rho1,
             const double* __restrict__ rrsetup)
{
  cg::grid_group grid = cg::this_grid();
  __shared__ float4 sw[2][JCH];              // 2u_j (double-buffered)     32 KB
  __shared__ float4 sa[2][JCH];              // (n_j, pn0, pn1, -)         32 KB
  __shared__ float qred[IPB][2][NJS + 2];    // js-fast, padded          33.3 KB
  __shared__ float pred[IPB][2][8];          //                             2 KB
  __shared__ double s1[TPB], s2[TPB], s3[TPB];                          // 12 KB
  __shared__ double sc[4];                   // a0,a1,b0,b1

  int tid = threadIdx.x;
  int blk = blockIdx.x;
  int ig = tid >> 7;                         // 0..3
  int js = tid & (NJS - 1);                  // 0..127
  int irow0 = blk * IPB + ig * IB;

  float4 ui[IB];
  float ni[IB];
#pragma unroll
  for (int k = 0; k < IB; ++k) { ui[k] = U4[irow0 + k]; ni[k] = NS[irow0 + k]; }

  // owned CG state in registers: tid < 64 owns (i = blk*32 + tid/2, col = tid&1)
  int oidx = blk * 64 + tid;                 // valid for tid<64
  double r_o = 0.0, p_o = 0.0, q_o = 0.0, x_o = 0.0;
  if (tid < 64) r_o = (double)Z[oidx];

  for (int t = 0; t < T_ITERS; ++t) {
    const float4* SAr = (t & 1) ? SA0 : SA1;
    const float4* SBr = (t & 1) ? SB0 : SB1;
    float4* SAw = (t & 1) ? SA1 : SA0;
    float4* SBw = (t & 1) ? SB1 : SB0;
    const double* partr = (t & 1) ? part0 : part1;
    double* partw = (t & 1) ? part1 : part0;
    const double* rhor = (t & 1) ? rho0 : rho1;
    double* rhow = (t & 1) ? rho1 : rho0;

    // ---- scalar phase (redundant per block, deterministic) ----
    if (t == 0) {
      s1[tid] = (tid < 64) ? rrsetup[tid] : 0.0;
      __syncthreads();
      for (int st = 32; st >= 2; st >>= 1) {
        if (tid < st) s1[tid] += s1[tid + st];
        __syncthreads();
      }
      if (tid < 2) { rhow[tid] = s1[tid]; sc[tid] = 0.0; sc[2 + tid] = 0.0; }
      __syncthreads();
    } else {
      s1[tid] = partr[tid];
      s2[tid] = partr[512 + tid];
      s3[tid] = partr[1024 + tid];
      __syncthreads();
      for (int st = 256; st >= 2; st >>= 1) {
        if (tid < st) {
          s1[tid] += s1[tid + st];
          s2[tid] += s2[tid + st];
          s3[tid] += s3[tid + st];
        }
        __syncthreads();
      }
      if (tid < 2) {
        double rho_o = rhor[tid];
        double al = rho_o / s1[tid];
        double rho_n = fma(al, fma(al, s3[tid], -2.0 * s2[tid]), rho_o);
        rhow[tid] = rho_n;
        sc[tid] = al;
        sc[2 + tid] = rho_n / rho_o;
      }
      __syncthreads();
    }
    double da0 = sc[0], da1 = sc[1], db0 = sc[2], db1 = sc[3];
    float a0 = (float)da0, a1 = (float)da1, b0 = (float)db0, b1 = (float)db1;

    // ---- matvec over all j, double-buffered chunks, IB=8 i per thread ----
    float4 w_r[2], sa_r[2];
#define LOADC(c) { int base = (c) * JCH;                                   \
      _Pragma("unroll")                                                     \
      for (int k = 0; k < 2; ++k) {                                         \
        int j = base + tid + k * TPB;                                       \
        w_r[k] = W4[j];                                                     \
        float4 s = SAr[j];                                                  \
        float4 qv = SBr[j];                                                 \
        float pn0 = fmaf(b0, s.z, fmaf(-a0, qv.x, s.x));                    \
        float pn1 = fmaf(b1, s.w, fmaf(-a1, qv.y, s.y));                    \
        sa_r[k] = make_float4(qv.z, pn0, pn1, 0.f);                         \
      } }
#define WRITEC(buf) { _Pragma("unroll")                                     \
      for (int k = 0; k < 2; ++k) {                                         \
        int u = tid + k * TPB;                                              \
        sw[buf][u] = w_r[k];                                                \
        sa[buf][u] = sa_r[k];                                               \
      } }
    float qa0[IB], qa1[IB];
#pragma unroll
    for (int k = 0; k < IB; ++k) { qa0[k] = 0.f; qa1[k] = 0.f; }
    LOADC(0);
    WRITEC(0);
    for (int c = 0; c < NJCH; ++c) {
      if (c + 1 < NJCH) LOADC(c + 1);
      __syncthreads();                       // buf[c&1] writes visible
      int bsel = c & 1;
#pragma unroll
      for (int jj = 0; jj < JPTC; ++jj) {
        int jl = jj * NJS + js;              // lanes read consecutive float4s
        float4 w = sw[bsel][jl];
        float4 aa = sa[bsel][jl];
#pragma unroll
        for (int k = 0; k < IB; ++k) {
          float ttn = -(ni[k] + aa.x);
          ttn = fmaf(ui[k].x, w.x, ttn);
          ttn = fmaf(ui[k].y, w.y, ttn);
          ttn = fmaf(ui[k].z, w.z, ttn);
          ttn = fmaf(ui[k].w, w.w, ttn);
          float e = EXP2F(ttn);
          qa0[k] = fmaf(e, aa.y, qa0[k]);
          qa1[k] = fmaf(e, aa.z, qa1[k]);
        }
      }
      if (c + 1 < NJCH) WRITEC((c + 1) & 1); // other buffer: race-free
    }
#pragma unroll
    for (int k = 0; k < IB; ++k) {           // js-fast writes: conflict-free
      qred[ig * IB + k][0][js] = qa0[k];
      qred[ig * IB + k][1][js] = qa1[k];
    }
    __syncthreads();

    // ---- stage-1 q reduction: 512 threads, each sums 16 slices ----
    {
      int il = tid >> 4, cc = (tid >> 3) & 1, pp = tid & 7;
      float s = 0.f;
#pragma unroll
      for (int k = 0; k < 16; ++k) s += qred[il][cc][pp * 16 + k];
      pred[il][cc][pp] = s;
    }
    __syncthreads();

    // ---- epilogue: owned rows, f64 recurrence in registers ----
    double pqv = 0.0, rqv = 0.0, qqv = 0.0;
    if (tid < 64) {
      int io = tid >> 1, col = tid & 1;
      double qg = 0.0;
#pragma unroll
      for (int p = 0; p < 8; ++p) qg += (double)pred[io][col][p];
      double al = col ? da1 : da0;
      double be = col ? db1 : db0;
      double rn = fma(-al, q_o, r_o);
      double pn = fma(be, p_o, rn);
      double xn = fma(al, p_o, x_o);
      double qn = fma((double)NUG, pn, qg);
      r_o = rn; p_o = pn; q_o = qn; x_o = xn;
      int i = blk * IPB + io;
      float* SAf = (float*)SAw;
      float* SBf = (float*)SBw;
      SAf[i * 4 + col] = (float)rn;          // r0,r1
      SAf[i * 4 + 2 + col] = (float)pn;      // p0,p1
      SBf[i * 4 + col] = (float)qn;          // q0,q1 (comp 2 = n, untouched)
      pqv = pn * qn;
      rqv = rn * qn;
      qqv = qn * qn;
    }
    s1[tid] = pqv; s2[tid] = rqv; s3[tid] = qqv;
    __syncthreads();
    for (int st = 32; st >= 2; st >>= 1) {
      if (tid < st) {
        s1[tid] += s1[tid + st];
        s2[tid] += s2[tid + st];
        s3[tid] += s3[tid + st];
      }
      __syncthreads();
    }
    if (tid < 2) {
      partw[blk * 2 + tid] = s1[tid];
      partw[512 + blk * 2 + tid] = s2[tid];
      partw[1024 + blk * 2 + tid] = s3[tid];
    }
    grid.sync();
  }
  if (tid < 64) {
    xout[oidx] = x_o;
    pout[oidx] = p_o;
  }
#undef LOADC
#undef WRITEC
}

// ---------------- final: last x half-step + combine ----------------
extern "C" __global__ void __launch_bounds__(TPB)
k_final(const float* __restrict__ Z, const double* __restrict__ x,
        const double* __restrict__ plast, const double* __restrict__ part_last,
        const double* __restrict__ rho_last, const double* __restrict__ mmdpart,
        float* __restrict__ out)
{
  __shared__ double s1[TPB];
  __shared__ double sc2[2];
  int tid = threadIdx.x;
  s1[tid] = part_last[tid];
  __syncthreads();
  for (int st = 256; st >= 2; st >>= 1) {
    if (tid < st) s1[tid] += s1[tid + st];
    __syncthreads();
  }
  if (tid < 2) sc2[tid] = rho_last[tid] / s1[tid];
  __syncthreads();
  double al = sc2[tid & 1];
  double zx = 0.0;
  for (int idx = tid; idx < N2; idx += TPB)   // stride even: parity fixed
    zx += (double)Z[idx] * fma(al, plast[idx], x[idx]);
  double ZX, S0, S1v, S2v;
  s1[tid] = zx;
  __syncthreads();
  for (int st = 256; st >= 1; st >>= 1) { if (tid < st) s1[tid] += s1[tid + st]; __syncthreads(); }
  ZX = s1[0]; __syncthreads();
  s1[tid] = (tid < 256) ? mmdpart[tid * 3 + 0] : 0.0;
  __syncthreads();
  for (int st = 256; st >= 1; st >>= 1) { if (tid < st) s1[tid] += s1[tid + st]; __syncthreads(); }
  S0 = s1[0]; __syncthreads();
  s1[tid] = (tid < 256) ? mmdpart[tid * 3 + 1] : 0.0;
  __syncthreads();
  for (int st = 256; st >= 1; st >>= 1) { if (tid < st) s1[tid] += s1[tid + st]; __syncthreads(); }
  S1v = s1[0]; __syncthreads();
  s1[tid] = (tid < 256) ? mmdpart[tid * 3 + 2] : 0.0;
  __syncthreads();
  for (int st = 256; st >= 1; st >>= 1) { if (tid < st) s1[tid] += s1[tid + st]; __syncthreads(); }
  S2v = s1[0];
  if (tid == 0) {
    double nn = (double)NPTS * (double)NPTS;
    double mmd = (S0 - 2.0 * S1v + S2v) / nn;
    out[0] = (float)(mmd + LAM * ZX);
  }
}

extern "C" void kernel_launch(void* const* d_in, const int* in_sizes, int n_in,
                              void* d_out, int out_size, void* d_ws, size_t ws_size,
                              hipStream_t stream)
{
  (void)in_sizes; (void)n_in; (void)out_size; (void)ws_size;
  const float* Xmu  = (const float*)d_in[0];
  const float* Yeta = (const float*)d_in[1];
  const float* Ymu  = (const float*)d_in[2];
  const float* Z    = (const float*)d_in[3];
  float* out = (float*)d_out;

  char* w = (char*)d_ws;
  float4* U4      = (float4*)(w);                      // 128K
  float4* W4      = (float4*)(w + (128 << 10));        // 128K
  float*  NS      = (float*)(w + (256 << 10));         // 32K
  float4* M4      = (float4*)(w + (288 << 10));        // 128K
  float4* Y4      = (float4*)(w + (416 << 10));        // 128K
  float4* SA0     = (float4*)(w + (544 << 10));        // 128K
  float4* SA1     = (float4*)(w + (672 << 10));        // 128K
  float4* SB0     = (float4*)(w + (800 << 10));        // 128K
  float4* SB1     = (float4*)(w + (928 << 10));        // 128K
  double* xout    = (double*)(w + (1056 << 10));       // 128K
  double* pout    = (double*)(w + (1184 << 10));       // 128K
  double* part0   = (double*)(w + (1312 << 10));       // 12.3K
  double* part1   = (double*)(w + (1328 << 10));       // 12.3K
  double* rho0    = (double*)(w + (1344 << 10));
  double* rho1    = (double*)(w + (1344 << 10) + 64);
  double* rrsetup = (double*)(w + (1345 << 10));       // 512B
  double* mmdpart = (double*)(w + (1346 << 10));       // 6K

  hipLaunchKernelGGL(k_setup, dim3(N2 / TPB), dim3(TPB), 0, stream,
                     Xmu, Yeta, Ymu, Z, U4, W4, NS, M4, Y4, SA1, SB0, SB1, rrsetup);
  hipLaunchKernelGGL(k_mmd, dim3(256), dim3(MTPB), 0, stream, M4, Y4, mmdpart);

  {
    const float4* a0 = U4; const float4* a1 = W4;
    const float* a2 = NS; const float* a3 = Z;
    float4* a4 = SA0; float4* a5 = SA1; float4* a6 = SB0; float4* a7 = SB1;
    double* a8 = xout; double* a9 = pout;
    double* a10 = part0; double* a11 = part1;
    double* a12 = rho0; double* a13 = rho1;
    const double* a14 = rrsetup;
    void* args[] = {&a0, &a1, &a2, &a3, &a4, &a5, &a6, &a7,
                    &a8, &a9, &a10, &a11, &a12, &a13, &a14};
    hipLaunchCooperativeKernel((void*)k_cg_persist, dim3(NBLK), dim3(TPB),
                               args, 0, stream);
  }

  int last = (T_ITERS - 1) & 1;   // = 1
  hipLaunchKernelGGL(k_final, dim3(1), dim3(TPB), 0, stream,
                     Z, xout, pout, last ? part1 : part0,
                     last ? rho1 : rho0, mmdpart, out);
}

// Round 7
// 43444.138 us; speedup vs baseline: 1.8221x; 1.6902x over previous
//
#include <hip/hip_runtime.h>

#define NPTS 8192
#define N2 (NPTS * 2)
#define TPB 512
#define NBLK 512           // 2 blocks per CU
#define IPB 16             // i-rows owned per block
#define IB 8               // i-rows per thread (register-blocked)
#define NIG (IPB / IB)     // 2 i-groups
#define NJS (TPB / NIG)    // 256 j-slices
#define JCH 1024           // j chunk staged in LDS
#define NJCH (NPTS / JCH)  // 8
#define JPTC (JCH / NJS)   // 4 j per thread per chunk
#define T_ITERS 1152
#define NUG 1.0e-4
#define LAM 1.0e-5

#if __has_builtin(__builtin_amdgcn_exp2f)
#define EXP2F(x) __builtin_amdgcn_exp2f(x)
#else
#define EXP2F(x) __expf(0.6931471805599453f * (x))
#endif

// ---------------- setup ----------------
// u = x / sqrt(2 ln2)  =>  K_ij = 2^(-(|u_i|^2 + |u_j|^2 - 2 u_i.u_j))
extern "C" __global__ void __launch_bounds__(TPB)
k_setup(const float* __restrict__ Xmu, const float* __restrict__ Yeta,
        const float* __restrict__ Ymu, const float* __restrict__ Z,
        float4* __restrict__ U4, float4* __restrict__ W4, float* __restrict__ NS,
        float4* __restrict__ M4, float4* __restrict__ Y4,
        float4* __restrict__ SA1, float4* __restrict__ SB0, float4* __restrict__ SB1,
        double* __restrict__ r64, double* __restrict__ p64,
        double* __restrict__ q64, double* __restrict__ x64,
        double* __restrict__ rrsetup)
{
  const float c2 = 0.84932180028802f;        // 1/sqrt(2 ln 2)
  int tid = threadIdx.x;
  int idx = blockIdx.x * TPB + tid;          // 0..16383
  int i = idx >> 1;
  float z = Z[idx];
  r64[idx] = (double)z;
  p64[idx] = 0.0;
  q64[idx] = 0.0;
  x64[idx] = 0.0;
  if ((idx & 1) == 0) {
    float a0 = Xmu[2 * i], a1 = Xmu[2 * i + 1];
    float e0 = Yeta[2 * i], e1 = Yeta[2 * i + 1];
    float m0 = Ymu[2 * i], m1 = Ymu[2 * i + 1];
    float z0 = Z[2 * i], z1 = Z[2 * i + 1];
    float u0 = c2 * a0, u1 = c2 * a1, u2 = c2 * e0, u3 = c2 * e1;
    float n = fmaf(u3, u3, fmaf(u2, u2, fmaf(u1, u1, u0 * u0)));
    U4[i] = make_float4(u0, u1, u2, u3);
    W4[i] = make_float4(2.f * u0, 2.f * u1, 2.f * u2, 2.f * u3);
    NS[i] = n;
    M4[i] = make_float4(a0, a1, e0 + z0, e1 + z1);
    Y4[i] = make_float4(a0, a1, m0, m1);
    SA1[i] = make_float4(z0, z1, 0.f, 0.f);  // (r0,r1,p0,p1) for t=0
    SB0[i] = make_float4(0.f, 0.f, n, 0.f);  // (q0,q1,n,-) both slots carry n
    SB1[i] = make_float4(0.f, 0.f, n, 0.f);
  }
  __shared__ double sd[TPB];
  sd[tid] = (double)z * (double)z;
  __syncthreads();
  for (int st = TPB >> 1; st >= 2; st >>= 1) {
    if (tid < st) sd[tid] += sd[tid + st];
    __syncthreads();
  }
  if (tid < 2) rrsetup[blockIdx.x * 2 + tid] = sd[tid];  // 32 blocks x 2
}

// ---------------- MMD: three fused Gram sums ----------------
#define MTPB 256
#define MCH 1024
extern "C" __global__ void __launch_bounds__(MTPB)
k_mmd(const float4* __restrict__ M4, const float4* __restrict__ Y4,
      double* __restrict__ mmdpart)
{
  __shared__ float4 sM[MCH];
  __shared__ float4 sY[MCH];
  __shared__ double sred[MTPB];
  int tid = threadIdx.x;
  int blk = blockIdx.x;            // 256 = 32 itiles x 8 chunks
  int itile = blk >> 3;
  int ch = blk & 7;
  int j0 = ch * MCH;
  for (int u = tid; u < MCH; u += MTPB) {
    sM[u] = M4[j0 + u];
    sY[u] = Y4[j0 + u];
  }
  __syncthreads();
  int i = itile * MTPB + tid;
  float4 mi = M4[i];
  float4 yi = Y4[i];
  double szz = 0.0, szy = 0.0, syy = 0.0;
  for (int jj = 0; jj < MCH; ++jj) {
    float4 mj = sM[jj];
    float4 yj = sY[jj];
    float d0 = mi.x - mj.x, d1 = mi.y - mj.y;
    float a = fmaf(d1, d1, d0 * d0);
    float u0 = mi.z - mj.z, u1 = mi.w - mj.w;
    float v0 = mi.z - yj.z, v1 = mi.w - yj.w;
    float w0 = yi.z - yj.z, w1 = yi.w - yj.w;
    float dzz = fmaf(u0, u0, fmaf(u1, u1, a));
    float dzy = fmaf(v0, v0, fmaf(v1, v1, a));
    float dyy = fmaf(w0, w0, fmaf(w1, w1, a));
    szz += (double)__expf(-0.5f * dzz);
    szy += (double)__expf(-0.5f * dzy);
    syy += (double)__expf(-0.5f * dyy);
  }
  double v[3] = {szz, szy, syy};
  for (int k = 0; k < 3; ++k) {
    sred[tid] = v[k];
    __syncthreads();
    for (int st = MTPB >> 1; st >= 1; st >>= 1) {
      if (tid < st) sred[tid] += sred[tid + st];
      __syncthreads();
    }
    if (tid == 0) mmdpart[blk * 3 + k] = sred[0];
    __syncthreads();
  }
}

// ---------------- one CG iteration per launch ----------------
// 512 blocks x 512 threads, 2 blocks/CU. Block owns IPB=16 rows.
// ig = tid>>8 owns IB=8 i-rows in regs; js = tid&255 j-slice: 4 B LDS per pair.
// Scalar recurrence (redundant per block): al = rho/pq; rho' = rho - 2al*rq + al^2*qq.
// Staging recomputes f32 p_t on the fly: pn = be*p + (r - al*q) from packed f32 state.
// Owned-row f64 state (r64,p64,q64,x64) updated by owner only.
extern "C" __global__ void __launch_bounds__(TPB, 4)
k_cg(const float4* __restrict__ U4, const float4* __restrict__ W4,
     const float* __restrict__ NS,
     const float4* __restrict__ SAr, const float4* __restrict__ SBr,
     float4* __restrict__ SAw, float4* __restrict__ SBw,
     double* __restrict__ r64, double* __restrict__ p64,
     double* __restrict__ q64, double* __restrict__ x64,
     const double* __restrict__ partr, double* __restrict__ partw,
     const double* __restrict__ rhor, double* __restrict__ rhow,
     const double* __restrict__ rrsetup, int t)
{
  __shared__ float4 sw[JCH];                 // 2u_j                    16 KB
  __shared__ float4 sa[JCH];                 // (n_j, pn0, pn1, -)      16 KB
  __shared__ float qred[IPB][2][NJS + 2];    //                         33 KB
  __shared__ float pred[IPB][2][16];         //                          2 KB
  __shared__ double s1[TPB], s2[TPB], s3[TPB];                       // 12 KB
  __shared__ double sc[4];                   // a0,a1,b0,b1

  int tid = threadIdx.x;
  int blk = blockIdx.x;
  int ig = tid >> 8;                         // 0..1
  int js = tid & (NJS - 1);                  // 0..255
  int irow0 = blk * IPB + ig * IB;

  // ---- scalar phase (redundant per block, deterministic) ----
  if (t == 0) {
    s1[tid] = (tid < 64) ? rrsetup[tid] : 0.0;
    __syncthreads();
    for (int st = 32; st >= 2; st >>= 1) {
      if (tid < st) s1[tid] += s1[tid + st];
      __syncthreads();
    }
    if (tid < 2) { rhow[tid] = s1[tid]; sc[tid] = 0.0; sc[2 + tid] = 0.0; }
    __syncthreads();
  } else {
    s1[tid] = partr[tid] + partr[512 + tid];
    s2[tid] = partr[1024 + tid] + partr[1536 + tid];
    s3[tid] = partr[2048 + tid] + partr[2560 + tid];
    __syncthreads();
    for (int st = 256; st >= 2; st >>= 1) {
      if (tid < st) {
        s1[tid] += s1[tid + st];
        s2[tid] += s2[tid + st];
        s3[tid] += s3[tid + st];
      }
      __syncthreads();
    }
    if (tid < 2) {
      double rho_o = rhor[tid];
      double al = rho_o / s1[tid];
      double rho_n = fma(al, fma(al, s3[tid], -2.0 * s2[tid]), rho_o);
      rhow[tid] = rho_n;
      sc[tid] = al;
      sc[2 + tid] = rho_n / rho_o;
    }
    __syncthreads();
  }
  double da0 = sc[0], da1 = sc[1], db0 = sc[2], db1 = sc[3];
  float a0 = (float)da0, a1 = (float)da1, b0 = (float)db0, b1 = (float)db1;

  float4 ui[IB];
  float ni[IB];
#pragma unroll
  for (int k = 0; k < IB; ++k) { ui[k] = U4[irow0 + k]; ni[k] = NS[irow0 + k]; }

  // ---- matvec over all j: single LDS buffer + register prefetch ----
  float4 w_r[2], sa_r[2];
#define LOADC(c) { int base = (c) * JCH;                                   \
    _Pragma("unroll")                                                       \
    for (int k = 0; k < 2; ++k) {                                           \
      int j = base + tid + k * TPB;                                         \
      w_r[k] = W4[j];                                                       \
      float4 s = SAr[j];                                                    \
      float4 qv = SBr[j];                                                   \
      float pn0 = fmaf(b0, s.z, fmaf(-a0, qv.x, s.x));                      \
      float pn1 = fmaf(b1, s.w, fmaf(-a1, qv.y, s.y));                      \
      sa_r[k] = make_float4(qv.z, pn0, pn1, 0.f);                           \
    } }
#define WRITEC() { _Pragma("unroll")                                        \
    for (int k = 0; k < 2; ++k) {                                           \
      int u = tid + k * TPB;                                                \
      sw[u] = w_r[k];                                                       \
      sa[u] = sa_r[k];                                                      \
    } }
  float qa0[IB], qa1[IB];
#pragma unroll
  for (int k = 0; k < IB; ++k) { qa0[k] = 0.f; qa1[k] = 0.f; }
  LOADC(0);
  WRITEC();
  __syncthreads();
  for (int c = 0; c < NJCH; ++c) {
    if (c + 1 < NJCH) LOADC(c + 1);          // prefetch next chunk into regs
#pragma unroll
    for (int jj = 0; jj < JPTC; ++jj) {
      int jl = jj * NJS + js;                // lanes read consecutive float4s
      float4 w = sw[jl];
      float4 aa = sa[jl];
#pragma unroll
      for (int k = 0; k < IB; ++k) {
        float ttn = -(ni[k] + aa.x);
        ttn = fmaf(ui[k].x, w.x, ttn);
        ttn = fmaf(ui[k].y, w.y, ttn);
        ttn = fmaf(ui[k].z, w.z, ttn);
        ttn = fmaf(ui[k].w, w.w, ttn);
        float e = EXP2F(ttn);
        qa0[k] = fmaf(e, aa.y, qa0[k]);
        qa1[k] = fmaf(e, aa.z, qa1[k]);
      }
    }
    __syncthreads();                         // everyone done reading LDS
    if (c + 1 < NJCH) {
      WRITEC();
      __syncthreads();                       // LDS ready for next chunk
    }
  }
#pragma unroll
  for (int k = 0; k < IB; ++k) {             // js-fast writes: conflict-free
    qred[ig * IB + k][0][js] = qa0[k];
    qred[ig * IB + k][1][js] = qa1[k];
  }
  __syncthreads();

  // ---- stage-1 q reduction: 512 threads, each sums 16 slices ----
  {
    int il = tid >> 5, cc = (tid >> 4) & 1, pp = tid & 15;
    float s = 0.f;
#pragma unroll
    for (int k = 0; k < 16; ++k) s += qred[il][cc][pp * 16 + k];
    pred[il][cc][pp] = s;
  }
  __syncthreads();

  // ---- epilogue: owned rows, f64 recurrence ----
  double pqv = 0.0, rqv = 0.0, qqv = 0.0;
  if (tid < 2 * IPB) {
    int io = tid >> 1, col = tid & 1;
    int oidx = blk * (2 * IPB) + tid;
    double qg = 0.0;
#pragma unroll
    for (int p = 0; p < 16; ++p) qg += (double)pred[io][col][p];
    double al = col ? da1 : da0;
    double be = col ? db1 : db0;
    double rold = r64[oidx], pold = p64[oidx], qold = q64[oidx];
    double rn = fma(-al, qold, rold);
    double pn = fma(be, pold, rn);
    double xn = fma(al, pold, x64[oidx]);
    double qn = fma((double)NUG, pn, qg);
    r64[oidx] = rn; p64[oidx] = pn; q64[oidx] = qn; x64[oidx] = xn;
    int i = blk * IPB + io;
    float* SAf = (float*)SAw;
    float* SBf = (float*)SBw;
    SAf[i * 4 + col] = (float)rn;            // r0,r1
    SAf[i * 4 + 2 + col] = (float)pn;        // p0,p1
    SBf[i * 4 + col] = (float)qn;            // q0,q1 (comp 2 = n, untouched)
    pqv = pn * qn;
    rqv = rn * qn;
    qqv = qn * qn;
  }
  s1[tid] = pqv; s2[tid] = rqv; s3[tid] = qqv;
  __syncthreads();
  for (int st = IPB; st >= 2; st >>= 1) {
    if (tid < st) {
      s1[tid] += s1[tid + st];
      s2[tid] += s2[tid + st];
      s3[tid] += s3[tid + st];
    }
    __syncthreads();
  }
  if (tid < 2) {
    partw[blk * 2 + tid] = s1[tid];
    partw[1024 + blk * 2 + tid] = s2[tid];
    partw[2048 + blk * 2 + tid] = s3[tid];
  }
#undef LOADC
#undef WRITEC
}

// ---------------- final: last x half-step + combine ----------------
extern "C" __global__ void __launch_bounds__(TPB)
k_final(const float* __restrict__ Z, const double* __restrict__ x,
        const double* __restrict__ plast, const double* __restrict__ part_last,
        const double* __restrict__ rho_last, const double* __restrict__ mmdpart,
        float* __restrict__ out)
{
  __shared__ double s1[TPB];
  __shared__ double sc2[2];
  int tid = threadIdx.x;
  s1[tid] = part_last[tid] + part_last[512 + tid];
  __syncthreads();
  for (int st = 256; st >= 2; st >>= 1) {
    if (tid < st) s1[tid] += s1[tid + st];
    __syncthreads();
  }
  if (tid < 2) sc2[tid] = rho_last[tid] / s1[tid];
  __syncthreads();
  double al = sc2[tid & 1];
  double zx = 0.0;
  for (int idx = tid; idx < N2; idx += TPB)   // stride even: parity fixed
    zx += (double)Z[idx] * fma(al, plast[idx], x[idx]);
  double ZX, S0, S1v, S2v;
  s1[tid] = zx;
  __syncthreads();
  for (int st = 256; st >= 1; st >>= 1) { if (tid < st) s1[tid] += s1[tid + st]; __syncthreads(); }
  ZX = s1[0]; __syncthreads();
  s1[tid] = (tid < 256) ? mmdpart[tid * 3 + 0] : 0.0;
  __syncthreads();
  for (int st = 256; st >= 1; st >>= 1) { if (tid < st) s1[tid] += s1[tid + st]; __syncthreads(); }
  S0 = s1[0]; __syncthreads();
  s1[tid] = (tid < 256) ? mmdpart[tid * 3 + 1] : 0.0;
  __syncthreads();
  for (int st = 256; st >= 1; st >>= 1) { if (tid < st) s1[tid] += s1[tid + st]; __syncthreads(); }
  S1v = s1[0]; __syncthreads();
  s1[tid] = (tid < 256) ? mmdpart[tid * 3 + 2] : 0.0;
  __syncthreads();
  for (int st = 256; st >= 1; st >>= 1) { if (tid < st) s1[tid] += s1[tid + st]; __syncthreads(); }
  S2v = s1[0];
  if (tid == 0) {
    double nn = (double)NPTS * (double)NPTS;
    double mmd = (S0 - 2.0 * S1v + S2v) / nn;
    out[0] = (float)(mmd + LAM * ZX);
  }
}

extern "C" void kernel_launch(void* const* d_in, const int* in_sizes, int n_in,
                              void* d_out, int out_size, void* d_ws, size_t ws_size,
                              hipStream_t stream)
{
  (void)in_sizes; (void)n_in; (void)out_size; (void)ws_size;
  const float* Xmu  = (const float*)d_in[0];
  const float* Yeta = (const float*)d_in[1];
  const float* Ymu  = (const float*)d_in[2];
  const float* Z    = (const float*)d_in[3];
  float* out = (float*)d_out;

  char* w = (char*)d_ws;
  float4* U4      = (float4*)(w);                      // 128K
  float4* W4      = (float4*)(w + (128 << 10));        // 128K
  float*  NS      = (float*)(w + (256 << 10));         // 32K
  float4* M4      = (float4*)(w + (288 << 10));        // 128K
  float4* Y4      = (float4*)(w + (416 << 10));        // 128K
  float4* SA[2]   = { (float4*)(w + (544 << 10)), (float4*)(w + (672 << 10)) };
  float4* SB[2]   = { (float4*)(w + (800 << 10)), (float4*)(w + (928 << 10)) };
  double* r64     = (double*)(w + (1056 << 10));       // 128K
  double* p64     = (double*)(w + (1184 << 10));       // 128K
  double* q64     = (double*)(w + (1312 << 10));       // 128K
  double* x64     = (double*)(w + (1440 << 10));       // 128K
  double* part[2] = { (double*)(w + (1568 << 10)), (double*)(w + (1600 << 10)) }; // 24K each
  double* rho[2]  = { (double*)(w + (1632 << 10)), (double*)(w + (1632 << 10) + 64) };
  double* rrsetup = (double*)(w + (1633 << 10));       // 512B
  double* mmdpart = (double*)(w + (1634 << 10));       // 6K

  hipLaunchKernelGGL(k_setup, dim3(N2 / TPB), dim3(TPB), 0, stream,
                     Xmu, Yeta, Ymu, Z, U4, W4, NS, M4, Y4,
                     SA[1], SB[0], SB[1], r64, p64, q64, x64, rrsetup);
  hipLaunchKernelGGL(k_mmd, dim3(256), dim3(MTPB), 0, stream, M4, Y4, mmdpart);

  for (int t = 0; t < T_ITERS; ++t) {
    int cur = t & 1, prv = cur ^ 1;
    hipLaunchKernelGGL(k_cg, dim3(NBLK), dim3(TPB), 0, stream,
                       U4, W4, NS, SA[prv], SB[prv], SA[cur], SB[cur],
                       r64, p64, q64, x64,
                       part[prv], part[cur], rho[prv], rho[cur], rrsetup, t);
  }
  int last = (T_ITERS - 1) & 1;   // = 1
  hipLaunchKernelGGL(k_final, dim3(1), dim3(TPB), 0, stream,
                     Z, x64, p64, part[last], rho[last], mmdpart, out);
}

// Round 8
// 32009.021 us; speedup vs baseline: 2.4731x; 1.3572x over previous
//
#include <hip/hip_runtime.h>

#define NPTS 8192
#define N2 (NPTS * 2)
#define TPB 512
#define NCH 16             // j-chunks
#define JCH (NPTS / NCH)   // 512 j per chunk
#define ITILE 256          // i-rows per block
#define NIT (NPTS / ITILE) // 32 i-tiles
#define NBLK (NIT * NCH)   // 512 matvec blocks (2/CU)
#define IB 8               // i-rows per thread
#define NIG (ITILE / IB)   // 32 i-groups
#define NJS (TPB / NIG)    // 16 j-slices
#define JPT (JCH / NJS)    // 32 j per thread
#define T_ITERS 1280
#define NUG 1.0e-4
#define LAM 1.0e-5

#if __has_builtin(__builtin_amdgcn_exp2f)
#define EXP2F(x) __builtin_amdgcn_exp2f(x)
#else
#define EXP2F(x) __expf(0.6931471805599453f * (x))
#endif

// ---------------- setup ----------------
// u = x / sqrt(2 ln2)  =>  K_ij = 2^(-(n_i + n_j - u_i . w_j)), w = 2u
extern "C" __global__ void __launch_bounds__(256)
k_setup(const float* __restrict__ Xmu, const float* __restrict__ Yeta,
        const float* __restrict__ Ymu, const float* __restrict__ Z,
        float4* __restrict__ U4, float4* __restrict__ W4, float* __restrict__ NS,
        float4* __restrict__ M4, float4* __restrict__ Y4,
        float2* __restrict__ Rf, float2* __restrict__ Pf0, float2* __restrict__ Pf1,
        double* __restrict__ r64, double* __restrict__ x64,
        double* __restrict__ rrpart)
{
  const float c2 = 0.84932180028802f;        // 1/sqrt(2 ln 2)
  int tid = threadIdx.x;
  int idx = blockIdx.x * 256 + tid;          // 0..16383 (64 blocks)
  int i = idx >> 1;
  float z = Z[idx];
  r64[idx] = (double)z;
  x64[idx] = 0.0;
  ((float*)Rf)[idx] = z;
  ((float*)Pf0)[idx] = 0.f;
  ((float*)Pf1)[idx] = 0.f;
  if ((idx & 1) == 0) {
    float a0 = Xmu[2 * i], a1 = Xmu[2 * i + 1];
    float e0 = Yeta[2 * i], e1 = Yeta[2 * i + 1];
    float m0 = Ymu[2 * i], m1 = Ymu[2 * i + 1];
    float z0 = Z[2 * i], z1 = Z[2 * i + 1];
    float u0 = c2 * a0, u1 = c2 * a1, u2 = c2 * e0, u3 = c2 * e1;
    float n = fmaf(u3, u3, fmaf(u2, u2, fmaf(u1, u1, u0 * u0)));
    U4[i] = make_float4(u0, u1, u2, u3);
    W4[i] = make_float4(2.f * u0, 2.f * u1, 2.f * u2, 2.f * u3);
    NS[i] = n;
    M4[i] = make_float4(a0, a1, e0 + z0, e1 + z1);
    Y4[i] = make_float4(a0, a1, m0, m1);
  }
  // rho_0 partials (parity-preserving): 64 blocks x 2 -> rrpart[0..127]
  __shared__ double sd[256];
  sd[tid] = (double)z * (double)z;
  __syncthreads();
  for (int st = 128; st >= 2; st >>= 1) {
    if (tid < st) sd[tid] += sd[tid + st];
    __syncthreads();
  }
  if (tid < 2) rrpart[blockIdx.x * 2 + tid] = sd[tid];
}

// ---------------- MMD: three fused Gram sums ----------------
#define MTPB 256
#define MCH 1024
extern "C" __global__ void __launch_bounds__(MTPB)
k_mmd(const float4* __restrict__ M4, const float4* __restrict__ Y4,
      double* __restrict__ mmdpart)
{
  __shared__ float4 sM[MCH];
  __shared__ float4 sY[MCH];
  __shared__ double sred[MTPB];
  int tid = threadIdx.x;
  int blk = blockIdx.x;            // 256 = 32 itiles x 8 chunks
  int itile = blk >> 3;
  int ch = blk & 7;
  int j0 = ch * MCH;
  for (int u = tid; u < MCH; u += MTPB) {
    sM[u] = M4[j0 + u];
    sY[u] = Y4[j0 + u];
  }
  __syncthreads();
  int i = itile * MTPB + tid;
  float4 mi = M4[i];
  float4 yi = Y4[i];
  double szz = 0.0, szy = 0.0, syy = 0.0;
  for (int jj = 0; jj < MCH; ++jj) {
    float4 mj = sM[jj];
    float4 yj = sY[jj];
    float d0 = mi.x - mj.x, d1 = mi.y - mj.y;
    float a = fmaf(d1, d1, d0 * d0);
    float u0 = mi.z - mj.z, u1 = mi.w - mj.w;
    float v0 = mi.z - yj.z, v1 = mi.w - yj.w;
    float w0 = yi.z - yj.z, w1 = yi.w - yj.w;
    float dzz = fmaf(u0, u0, fmaf(u1, u1, a));
    float dzy = fmaf(v0, v0, fmaf(v1, v1, a));
    float dyy = fmaf(w0, w0, fmaf(w1, w1, a));
    szz += (double)__expf(-0.5f * dzz);
    szy += (double)__expf(-0.5f * dzy);
    syy += (double)__expf(-0.5f * dyy);
  }
  double v[3] = {szz, szy, syy};
  for (int k = 0; k < 3; ++k) {
    sred[tid] = v[k];
    __syncthreads();
    for (int st = MTPB >> 1; st >= 1; st >>= 1) {
      if (tid < st) sred[tid] += sred[tid + st];
      __syncthreads();
    }
    if (tid == 0) mmdpart[blk * 3 + k] = sred[0];
    __syncthreads();
  }
}

// ---------------- CG matvec: j-chunked, IB=8, shuffle q-reduce ----------------
// Block (it, ch): i in [it*256, +256), j in [ch*512, +512).
// beta from rrpart parity ping-pong; p_t = r + beta*p staged f32 on the fly.
// Owner block (ch == it&15) writes p_t; chunk q-partials to qpart; <p,q>+eta<p,p>
// partials to pqpart.
extern "C" __global__ void __launch_bounds__(TPB, 4)
k_matvec(const float4* __restrict__ U4, const float4* __restrict__ W4,
         const float* __restrict__ NS,
         const float2* __restrict__ Rf, const float2* __restrict__ Pfp,
         float2* __restrict__ Pfc, float2* __restrict__ qpart,  // [NCH][NPTS]
         double* __restrict__ pqpart, const double* __restrict__ rrpart, int t)
{
  __shared__ float4 sw[JCH];                 // w_j = 2u_j           8 KB
  __shared__ float4 sa[JCH];                 // (n_j, pn0, pn1, -)   8 KB
  __shared__ double s1[TPB], s2[TPB];        //                      8 KB
  __shared__ double sc[2];                   // b0, b1
  int tid = threadIdx.x;
  int blk = blockIdx.x;
  int it = blk >> 4;
  int ch = blk & (NCH - 1);
  int j = ch * JCH + tid;                    // one j per thread

  // issue staging loads early (hide L2/L3 latency under beta phase)
  float4 wj = W4[j];
  float nj = NS[j];
  float2 rj = Rf[j];
  float2 pj = Pfp[j];

  // ---- beta phase ----
  if (t == 0) {
    if (tid < 2) sc[tid] = 0.0;
    __syncthreads();
  } else {
    const double* cur = rrpart + (t & 1) * 128;        // rho_t partials
    const double* prv = rrpart + ((t - 1) & 1) * 128;  // rho_{t-1}
    if (tid < 128) { s1[tid] = cur[tid]; s2[tid] = prv[tid]; }
    __syncthreads();
    for (int st = 64; st >= 2; st >>= 1) {
      if (tid < st) { s1[tid] += s1[tid + st]; s2[tid] += s2[tid + st]; }
      __syncthreads();
    }
    if (tid < 2) sc[tid] = s1[tid] / s2[tid];
    __syncthreads();
  }
  float b0 = (float)sc[0], b1 = (float)sc[1];

  // ---- stage chunk ----
  sw[tid] = wj;
  sa[tid] = make_float4(nj, fmaf(b0, pj.x, rj.x), fmaf(b1, pj.y, rj.y), 0.f);
  __syncthreads();

  // ---- inner: IB=8 i-rows x 32 j per thread ----
  int js = tid & (NJS - 1);                  // 0..15
  int ig = tid >> 4;                         // 0..31
  int i0 = it * ITILE + ig * IB;
  float4 ui[IB];
  float ni[IB];
#pragma unroll
  for (int k = 0; k < IB; ++k) { ui[k] = U4[i0 + k]; ni[k] = NS[i0 + k]; }
  float qa0[IB], qa1[IB];
#pragma unroll
  for (int k = 0; k < IB; ++k) { qa0[k] = 0.f; qa1[k] = 0.f; }
#pragma unroll 4
  for (int jj = 0; jj < JPT; ++jj) {
    int jl = jj * NJS + js;                  // 4-lane broadcast, 2-way banks: free
    float4 w = sw[jl];
    float4 aa = sa[jl];
#pragma unroll
    for (int k = 0; k < IB; ++k) {
      float ttn = -(ni[k] + aa.x);
      ttn = fmaf(ui[k].x, w.x, ttn);
      ttn = fmaf(ui[k].y, w.y, ttn);
      ttn = fmaf(ui[k].z, w.z, ttn);
      ttn = fmaf(ui[k].w, w.w, ttn);
      float e = EXP2F(ttn);
      qa0[k] = fmaf(e, aa.y, qa0[k]);
      qa1[k] = fmaf(e, aa.z, qa1[k]);
    }
  }
  // ---- reduce across 16 j-slices via shuffles (width 16) ----
#pragma unroll
  for (int k = 0; k < IB; ++k) {
#pragma unroll
    for (int d = 8; d >= 1; d >>= 1) {
      qa0[k] += __shfl_down(qa0[k], (unsigned)d, 16);
      qa1[k] += __shfl_down(qa1[k], (unsigned)d, 16);
    }
  }
  // ---- epilogue: js==0 lanes hold full chunk-q for 8 rows ----
  double pq0 = 0.0, pq1 = 0.0;
  if (js == 0) {
    int owner = (it & (NCH - 1));
#pragma unroll
    for (int k = 0; k < IB; ++k) {
      int i = i0 + k;
      float2 ri = Rf[i];
      float2 pi = Pfp[i];
      float pn0 = fmaf(b0, pi.x, ri.x);
      float pn1 = fmaf(b1, pi.y, ri.y);
      qpart[(size_t)ch * NPTS + i] = make_float2(qa0[k], qa1[k]);
      if (ch == owner) Pfc[i] = make_float2(pn0, pn1);
      pq0 += (double)pn0 * (double)qa0[k];
      pq1 += (double)pn1 * (double)qa1[k];
      if (ch == 0) {                         // + eta <p,p>, added exactly once
        pq0 += NUG * (double)pn0 * (double)pn0;
        pq1 += NUG * (double)pn1 * (double)pn1;
      }
    }
  }
  s1[tid] = pq0;
  s2[tid] = pq1;
  __syncthreads();
  for (int st = TPB >> 1; st >= 1; st >>= 1) {
    if (tid < st) { s1[tid] += s1[tid + st]; s2[tid] += s2[tid + st]; }
    __syncthreads();
  }
  if (tid == 0) { pqpart[blk * 2 + 0] = s1[0]; pqpart[blk * 2 + 1] = s2[0]; }
}

// ---------------- CG update: alpha, x/r update, rho partials ----------------
extern "C" __global__ void __launch_bounds__(256)
k_update(const float* __restrict__ qpartf, const float* __restrict__ Pfcf,
         double* __restrict__ r64, double* __restrict__ x64,
         float* __restrict__ Rff,
         const double* __restrict__ pqpart, double* __restrict__ rrpart, int t)
{
  __shared__ double s1[256];
  __shared__ double s2[128];
  __shared__ double alpha[2];
  int tid = threadIdx.x;
  {
    // pq total (1024 entries, parity-preserving) and rho_t (128 entries)
    double a = pqpart[tid] + pqpart[tid + 256] + pqpart[tid + 512] + pqpart[tid + 768];
    s1[tid] = a;
    if (tid < 128) s2[tid] = rrpart[(t & 1) * 128 + tid];
    __syncthreads();
    for (int st = 128; st >= 2; st >>= 1) {
      if (tid < st) s1[tid] += s1[tid + st];
      if (st <= 64 && tid < st) s2[tid] += s2[tid + st];
      __syncthreads();
    }
    if (tid < 2) alpha[tid] = s2[tid] / s1[tid];
    __syncthreads();
  }
  int idx = blockIdx.x * 256 + tid;
  float pn = Pfcf[idx];
  double q = 0.0;
#pragma unroll
  for (int c = 0; c < NCH; ++c) q += (double)qpartf[(size_t)c * N2 + idx];
  q = fma((double)NUG, (double)pn, q);
  double a = alpha[idx & 1];
  double rv = fma(-a, q, r64[idx]);
  x64[idx] = fma(a, (double)pn, x64[idx]);
  r64[idx] = rv;
  Rff[idx] = (float)rv;
  s1[tid] = rv * rv;
  __syncthreads();
  for (int st = 128; st >= 2; st >>= 1) {
    if (tid < st) s1[tid] += s1[tid + st];
    __syncthreads();
  }
  if (tid < 2)
    rrpart[((t + 1) & 1) * 128 + blockIdx.x * 2 + tid] = s1[tid];
}

// ---------------- final combine ----------------
extern "C" __global__ void __launch_bounds__(256)
k_final(const float* __restrict__ Z, const double* __restrict__ x64,
        const double* __restrict__ mmdpart, float* __restrict__ out)
{
  __shared__ double sred[256];
  int tid = threadIdx.x;
  double zx = 0.0;
  for (int idx = tid; idx < N2; idx += 256)
    zx += (double)Z[idx] * x64[idx];
  double acc[4];
  acc[0] = zx;
  acc[1] = mmdpart[tid * 3 + 0];
  acc[2] = mmdpart[tid * 3 + 1];
  acc[3] = mmdpart[tid * 3 + 2];
  double tot[4];
  for (int k = 0; k < 4; ++k) {
    sred[tid] = acc[k];
    __syncthreads();
    for (int st = 128; st >= 1; st >>= 1) {
      if (tid < st) sred[tid] += sred[tid + st];
      __syncthreads();
    }
    tot[k] = sred[0];
    __syncthreads();
  }
  if (tid == 0) {
    double nn = (double)NPTS * (double)NPTS;
    double mmd = (tot[1] - 2.0 * tot[2] + tot[3]) / nn;
    out[0] = (float)(mmd + LAM * tot[0]);
  }
}

extern "C" void kernel_launch(void* const* d_in, const int* in_sizes, int n_in,
                              void* d_out, int out_size, void* d_ws, size_t ws_size,
                              hipStream_t stream)
{
  (void)in_sizes; (void)n_in; (void)out_size; (void)ws_size;
  const float* Xmu  = (const float*)d_in[0];
  const float* Yeta = (const float*)d_in[1];
  const float* Ymu  = (const float*)d_in[2];
  const float* Z    = (const float*)d_in[3];
  float* out = (float*)d_out;

  char* w = (char*)d_ws;
  float4* U4      = (float4*)(w);                      // 128K
  float4* W4      = (float4*)(w + (128 << 10));        // 128K
  float*  NS      = (float*)(w + (256 << 10));         // 32K
  float4* M4      = (float4*)(w + (288 << 10));        // 128K
  float4* Y4      = (float4*)(w + (416 << 10));        // 128K
  float2* Rf      = (float2*)(w + (544 << 10));        // 64K
  float2* Pf[2]   = { (float2*)(w + (608 << 10)), (float2*)(w + (672 << 10)) };
  double* r64     = (double*)(w + (736 << 10));        // 128K
  double* x64     = (double*)(w + (864 << 10));        // 128K
  float2* qpart   = (float2*)(w + (992 << 10));        // 1M  [16][8192] float2
  double* pqpart  = (double*)(w + (2016 << 10));       // 8K  (512 blk x 2)
  double* rrpart  = (double*)(w + (2024 << 10));       // 2K  (2 parity x 128)
  double* mmdpart = (double*)(w + (2026 << 10));       // 6K

  hipLaunchKernelGGL(k_setup, dim3(64), dim3(256), 0, stream,
                     Xmu, Yeta, Ymu, Z, U4, W4, NS, M4, Y4,
                     Rf, Pf[0], Pf[1], r64, x64, rrpart);
  hipLaunchKernelGGL(k_mmd, dim3(256), dim3(MTPB), 0, stream, M4, Y4, mmdpart);

  for (int t = 0; t < T_ITERS; ++t) {
    float2* Pprev = Pf[(t + 1) & 1];
    float2* Pcur  = Pf[t & 1];
    hipLaunchKernelGGL(k_matvec, dim3(NBLK), dim3(TPB), 0, stream,
                       U4, W4, NS, Rf, Pprev, Pcur, qpart, pqpart, rrpart, t);
    hipLaunchKernelGGL(k_update, dim3(64), dim3(256), 0, stream,
                       (const float*)qpart, (const float*)Pcur,
                       r64, x64, (float*)Rf, pqpart, rrpart, t);
  }
  hipLaunchKernelGGL(k_final, dim3(1), dim3(256), 0, stream,
                     Z, x64, mmdpart, out);
}

// Round 9
// 31108.652 us; speedup vs baseline: 2.5447x; 1.0289x over previous
//
#include <hip/hip_runtime.h>

#define NPTS 8192
#define N2 (NPTS * 2)
#define TPB 512
#define NBLK 512           // 2 blocks/CU, full residency
#define IPB 16             // i-rows owned per block
#define IB 8               // i-rows per thread
#define NJS 256            // j-slices (tid & 255)
#define JPT (NPTS / NJS)   // 32 j per thread
#define T_ITERS 1152
#define NUG 1.0e-4
#define LAM 1.0e-5

#if __has_builtin(__builtin_amdgcn_exp2f)
#define EXP2F(x) __builtin_amdgcn_exp2f(x)
#else
#define EXP2F(x) __expf(0.6931471805599453f * (x))
#endif

// ---------------- setup ----------------
// u = x / sqrt(2 ln2)  =>  K_ij = 2^(u_i.w_j - n_i - n_j), w = 2u
extern "C" __global__ void __launch_bounds__(256)
k_setup(const float* __restrict__ Xmu, const float* __restrict__ Yeta,
        const float* __restrict__ Ymu, const float* __restrict__ Z,
        float4* __restrict__ U4, float4* __restrict__ W4, float* __restrict__ NS,
        float4* __restrict__ M4, float4* __restrict__ Y4,
        float4* __restrict__ SA1, float2* __restrict__ SB1,
        double* __restrict__ r64, double* __restrict__ p64,
        double* __restrict__ q64, double* __restrict__ x64,
        double* __restrict__ rrsetup)
{
  const float c2 = 0.84932180028802f;        // 1/sqrt(2 ln 2)
  int tid = threadIdx.x;
  int idx = blockIdx.x * 256 + tid;          // 0..16383 (64 blocks)
  int i = idx >> 1;
  float z = Z[idx];
  r64[idx] = (double)z;
  p64[idx] = 0.0;
  q64[idx] = 0.0;
  x64[idx] = 0.0;
  if ((idx & 1) == 0) {
    float a0 = Xmu[2 * i], a1 = Xmu[2 * i + 1];
    float e0 = Yeta[2 * i], e1 = Yeta[2 * i + 1];
    float m0 = Ymu[2 * i], m1 = Ymu[2 * i + 1];
    float z0 = Z[2 * i], z1 = Z[2 * i + 1];
    float u0 = c2 * a0, u1 = c2 * a1, u2 = c2 * e0, u3 = c2 * e1;
    float n = fmaf(u3, u3, fmaf(u2, u2, fmaf(u1, u1, u0 * u0)));
    U4[i] = make_float4(u0, u1, u2, u3);
    W4[i] = make_float4(2.f * u0, 2.f * u1, 2.f * u2, 2.f * u3);
    NS[i] = n;
    M4[i] = make_float4(a0, a1, e0 + z0, e1 + z1);
    Y4[i] = make_float4(a0, a1, m0, m1);
    SA1[i] = make_float4(z0, z1, 0.f, 0.f);  // (r0,r1,p0,p1) at t=0
    SB1[i] = make_float2(0.f, 0.f);          // (q0,q1) at t=0
  }
  __shared__ double sd[256];
  sd[tid] = (double)z * (double)z;
  __syncthreads();
  for (int st = 128; st >= 2; st >>= 1) {
    if (tid < st) sd[tid] += sd[tid + st];
    __syncthreads();
  }
  if (tid < 2) rrsetup[blockIdx.x * 2 + tid] = sd[tid];   // 128 entries
}

// ---------------- MMD: three fused Gram sums ----------------
#define MTPB 256
#define MCH 1024
extern "C" __global__ void __launch_bounds__(MTPB)
k_mmd(const float4* __restrict__ M4, const float4* __restrict__ Y4,
      double* __restrict__ mmdpart)
{
  __shared__ float4 sM[MCH];
  __shared__ float4 sY[MCH];
  __shared__ double sred[MTPB];
  int tid = threadIdx.x;
  int blk = blockIdx.x;            // 256 = 32 itiles x 8 chunks
  int itile = blk >> 3;
  int ch = blk & 7;
  int j0 = ch * MCH;
  for (int u = tid; u < MCH; u += MTPB) {
    sM[u] = M4[j0 + u];
    sY[u] = Y4[j0 + u];
  }
  __syncthreads();
  int i = itile * MTPB + tid;
  float4 mi = M4[i];
  float4 yi = Y4[i];
  double szz = 0.0, szy = 0.0, syy = 0.0;
  for (int jj = 0; jj < MCH; ++jj) {
    float4 mj = sM[jj];
    float4 yj = sY[jj];
    float d0 = mi.x - mj.x, d1 = mi.y - mj.y;
    float a = fmaf(d1, d1, d0 * d0);
    float u0 = mi.z - mj.z, u1 = mi.w - mj.w;
    float v0 = mi.z - yj.z, v1 = mi.w - yj.w;
    float w0 = yi.z - yj.z, w1 = yi.w - yj.w;
    float dzz = fmaf(u0, u0, fmaf(u1, u1, a));
    float dzy = fmaf(v0, v0, fmaf(v1, v1, a));
    float dyy = fmaf(w0, w0, fmaf(w1, w1, a));
    szz += (double)__expf(-0.5f * dzz);
    szy += (double)__expf(-0.5f * dzy);
    syy += (double)__expf(-0.5f * dyy);
  }
  double v[3] = {szz, szy, syy};
  for (int k = 0; k < 3; ++k) {
    sred[tid] = v[k];
    __syncthreads();
    for (int st = MTPB >> 1; st >= 1; st >>= 1) {
      if (tid < st) sred[tid] += sred[tid + st];
      __syncthreads();
    }
    if (tid == 0) mmdpart[blk * 3 + k] = sred[0];
    __syncthreads();
  }
}

// ---------------- fused CG iteration: one launch = one full step ----------------
// Scalars: al_t = rho_{t-1}/pq_{t-1}; rho_t = rho_{t-1} - 2 al rq + al^2 qq;
// be_t = rho_t/rho_{t-1}. Staging: pn_j = be*p + (r - al*q) from SA/SB (prev
// buffers) into LDS (full vector). Matvec q = G pn (+eta pn). Epilogue (owner,
// tid<32): f64 recurrence, write SA/SB (cur), partials pq/rq/qq.
extern "C" __global__ void __launch_bounds__(TPB, 4)
k_it(const float4* __restrict__ U4, const float4* __restrict__ W4,
     const float* __restrict__ NS,
     const float4* __restrict__ SAr, const float2* __restrict__ SBr,
     float4* __restrict__ SAw, float2* __restrict__ SBw,
     double* __restrict__ r64, double* __restrict__ p64,
     double* __restrict__ q64, double* __restrict__ x64,
     const double* __restrict__ partr, double* __restrict__ partw,
     const double* __restrict__ rhor, double* __restrict__ rhow,
     const double* __restrict__ rrsetup, int t)
{
  __shared__ float2 sp[NPTS];                // pn, full vector     64 KB
  __shared__ double s1[TPB], s2[TPB], s3[TPB];                  // 12 KB
  __shared__ float qred[8][IB][2];           // per-wave partials  512 B
  __shared__ double sc[4];                   // a0,a1,b0,b1

  int tid = threadIdx.x;
  int blk = blockIdx.x;

  // ---- scalar phase (redundant per block, deterministic) ----
  if (t == 0) {
    s1[tid] = (tid < 128) ? rrsetup[tid] : 0.0;
    __syncthreads();
    for (int st = 64; st >= 2; st >>= 1) {
      if (tid < st) s1[tid] += s1[tid + st];
      __syncthreads();
    }
    if (tid < 2) { rhow[tid] = s1[tid]; sc[tid] = 0.0; sc[2 + tid] = 0.0; }
    __syncthreads();
  } else {
    s1[tid] = partr[tid] + partr[tid + 512];
    s2[tid] = partr[1024 + tid] + partr[1536 + tid];
    s3[tid] = partr[2048 + tid] + partr[2560 + tid];
    __syncthreads();
    for (int st = 256; st >= 2; st >>= 1) {
      if (tid < st) {
        s1[tid] += s1[tid + st];
        s2[tid] += s2[tid + st];
        s3[tid] += s3[tid + st];
      }
      __syncthreads();
    }
    if (tid < 2) {
      double rho_o = rhor[tid];
      double al = rho_o / s1[tid];
      double rho_n = fma(al, fma(al, s3[tid], -2.0 * s2[tid]), rho_o);
      rhow[tid] = rho_n;                     // identical dup-write per block
      sc[tid] = al;
      sc[2 + tid] = rho_n / rho_o;
    }
    __syncthreads();
  }
  double da0 = sc[0], da1 = sc[1], db0 = sc[2], db1 = sc[3];
  float a0 = (float)da0, a1 = (float)da1, b0 = (float)db0, b1 = (float)db1;

  // ---- stage pn for ALL j into LDS (fresh traffic: 24 B/j) ----
  for (int u = tid; u < NPTS; u += TPB) {    // 16 coalesced iterations
    float4 s = SAr[u];
    float2 qv = SBr[u];
    sp[u] = make_float2(fmaf(b0, s.z, fmaf(-a0, qv.x, s.x)),
                        fmaf(b1, s.w, fmaf(-a1, qv.y, s.y)));
  }
  __syncthreads();

  // ---- matvec: IB=8 rows/thread, w/n streamed from L2, pn from LDS ----
  int ig = tid >> 8;                         // 0..1
  int js = tid & (NJS - 1);                  // 0..255
  int i0 = blk * IPB + ig * IB;
  float4 ui[IB];
  float ni[IB];
#pragma unroll
  for (int k = 0; k < IB; ++k) { ui[k] = U4[i0 + k]; ni[k] = NS[i0 + k]; }
  float qa0[IB], qa1[IB];
#pragma unroll
  for (int k = 0; k < IB; ++k) { qa0[k] = 0.f; qa1[k] = 0.f; }
#pragma unroll 4
  for (int jj = 0; jj < JPT; ++jj) {
    int j = jj * NJS + js;                   // coalesced across lanes
    float4 w = W4[j];
    float nj = NS[j];
    float2 pn = sp[j];
#pragma unroll
    for (int k = 0; k < IB; ++k) {
      float ttn = -(ni[k] + nj);
      ttn = fmaf(ui[k].x, w.x, ttn);
      ttn = fmaf(ui[k].y, w.y, ttn);
      ttn = fmaf(ui[k].z, w.z, ttn);
      ttn = fmaf(ui[k].w, w.w, ttn);
      float e = EXP2F(ttn);
      qa0[k] = fmaf(e, pn.x, qa0[k]);
      qa1[k] = fmaf(e, pn.y, qa1[k]);
    }
  }
  // ---- wave-level reduce over 64 lanes, then LDS across 4 waves/ig ----
#pragma unroll
  for (int k = 0; k < IB; ++k) {
#pragma unroll
    for (int d = 32; d >= 1; d >>= 1) {
      qa0[k] += __shfl_down(qa0[k], (unsigned)d, 64);
      qa1[k] += __shfl_down(qa1[k], (unsigned)d, 64);
    }
  }
  {
    int lane = tid & 63, wv = tid >> 6;      // waves 0-3: ig0, 4-7: ig1
    if (lane == 0) {
#pragma unroll
      for (int k = 0; k < IB; ++k) {
        qred[wv][k][0] = qa0[k];
        qred[wv][k][1] = qa1[k];
      }
    }
  }
  __syncthreads();

  // ---- epilogue: owner rows (tid<32), f64 recurrence ----
  double pqv = 0.0, rqv = 0.0, qqv = 0.0;
  if (tid < 2 * IPB) {
    int io = tid >> 1, col = tid & 1;
    int oidx = blk * (2 * IPB) + tid;
    int wb = (io >> 3) * 4, k = io & 7;
    double qg = (double)qred[wb][k][col] + (double)qred[wb + 1][k][col]
              + (double)qred[wb + 2][k][col] + (double)qred[wb + 3][k][col];
    double al = col ? da1 : da0;
    double be = col ? db1 : db0;
    double rold = r64[oidx], pold = p64[oidx], qold = q64[oidx];
    double rn = fma(-al, qold, rold);        // r_t
    double pn = fma(be, pold, rn);           // p_t
    double xn = fma(al, pold, x64[oidx]);    // x_t
    double qn = fma((double)NUG, pn, qg);    // q_t
    r64[oidx] = rn; p64[oidx] = pn; q64[oidx] = qn; x64[oidx] = xn;
    int i = blk * IPB + io;
    float* SAf = (float*)SAw;
    float* SBf = (float*)SBw;
    SAf[i * 4 + col] = (float)rn;
    SAf[i * 4 + 2 + col] = (float)pn;
    SBf[i * 2 + col] = (float)qn;
    pqv = pn * qn;
    rqv = rn * qn;
    qqv = qn * qn;
  }
  s1[tid] = pqv; s2[tid] = rqv; s3[tid] = qqv;
  __syncthreads();
  for (int st = IPB; st >= 2; st >>= 1) {
    if (tid < st) {
      s1[tid] += s1[tid + st];
      s2[tid] += s2[tid + st];
      s3[tid] += s3[tid + st];
    }
    __syncthreads();
  }
  if (tid < 2) {
    partw[blk * 2 + tid] = s1[tid];
    partw[1024 + blk * 2 + tid] = s2[tid];
    partw[2048 + blk * 2 + tid] = s3[tid];
  }
}

// ---------------- final: last x half-step + combine ----------------
extern "C" __global__ void __launch_bounds__(256)
k_final(const float* __restrict__ Z, const double* __restrict__ x64,
        const double* __restrict__ p64, const double* __restrict__ part_last,
        const double* __restrict__ rho_last, const double* __restrict__ mmdpart,
        float* __restrict__ out)
{
  __shared__ double s1[256];
  __shared__ double sc2[2];
  int tid = threadIdx.x;
  s1[tid] = part_last[tid] + part_last[256 + tid]
          + part_last[512 + tid] + part_last[768 + tid];
  __syncthreads();
  for (int st = 128; st >= 2; st >>= 1) {
    if (tid < st) s1[tid] += s1[tid + st];
    __syncthreads();
  }
  if (tid < 2) sc2[tid] = rho_last[tid] / s1[tid];
  __syncthreads();
  double al = sc2[tid & 1];
  double zx = 0.0;
  for (int idx = tid; idx < N2; idx += 256)   // stride even: parity fixed
    zx += (double)Z[idx] * fma(al, p64[idx], x64[idx]);
  double acc[4];
  acc[0] = zx;
  acc[1] = mmdpart[tid * 3 + 0];
  acc[2] = mmdpart[tid * 3 + 1];
  acc[3] = mmdpart[tid * 3 + 2];
  double tot[4];
  for (int k = 0; k < 4; ++k) {
    s1[tid] = acc[k];
    __syncthreads();
    for (int st = 128; st >= 1; st >>= 1) {
      if (tid < st) s1[tid] += s1[tid + st];
      __syncthreads();
    }
    tot[k] = s1[0];
    __syncthreads();
  }
  if (tid == 0) {
    double nn = (double)NPTS * (double)NPTS;
    double mmd = (tot[1] - 2.0 * tot[2] + tot[3]) / nn;
    out[0] = (float)(mmd + LAM * tot[0]);
  }
}

extern "C" void kernel_launch(void* const* d_in, const int* in_sizes, int n_in,
                              void* d_out, int out_size, void* d_ws, size_t ws_size,
                              hipStream_t stream)
{
  (void)in_sizes; (void)n_in; (void)out_size; (void)ws_size;
  const float* Xmu  = (const float*)d_in[0];
  const float* Yeta = (const float*)d_in[1];
  const float* Ymu  = (const float*)d_in[2];
  const float* Z    = (const float*)d_in[3];
  float* out = (float*)d_out;

  char* w = (char*)d_ws;
  float4* U4      = (float4*)(w);                      // 128K
  float4* W4      = (float4*)(w + (128 << 10));        // 128K
  float*  NS      = (float*)(w + (256 << 10));         // 32K
  float4* M4      = (float4*)(w + (288 << 10));        // 128K
  float4* Y4      = (float4*)(w + (416 << 10));        // 128K
  float4* SA[2]   = { (float4*)(w + (544 << 10)), (float4*)(w + (672 << 10)) };
  float2* SB[2]   = { (float2*)(w + (800 << 10)), (float2*)(w + (864 << 10)) };
  double* r64     = (double*)(w + (928 << 10));        // 128K
  double* p64     = (double*)(w + (1056 << 10));       // 128K
  double* q64     = (double*)(w + (1184 << 10));       // 128K
  double* x64     = (double*)(w + (1312 << 10));       // 128K
  double* part[2] = { (double*)(w + (1440 << 10)), (double*)(w + (1464 << 10)) };
  double* rho[2]  = { (double*)(w + (1488 << 10)), (double*)(w + (1488 << 10) + 64) };
  double* rrsetup = (double*)(w + (1489 << 10));       // 1K
  double* mmdpart = (double*)(w + (1490 << 10));       // 6K

  hipLaunchKernelGGL(k_setup, dim3(64), dim3(256), 0, stream,
                     Xmu, Yeta, Ymu, Z, U4, W4, NS, M4, Y4,
                     SA[1], SB[1], r64, p64, q64, x64, rrsetup);
  hipLaunchKernelGGL(k_mmd, dim3(256), dim3(MTPB), 0, stream, M4, Y4, mmdpart);

  for (int t = 0; t < T_ITERS; ++t) {
    int cur = t & 1, prv = cur ^ 1;
    hipLaunchKernelGGL(k_it, dim3(NBLK), dim3(TPB), 0, stream,
                       U4, W4, NS, SA[prv], SB[prv], SA[cur], SB[cur],
                       r64, p64, q64, x64,
                       part[prv], part[cur], rho[prv], rho[cur], rrsetup, t);
  }
  int last = (T_ITERS - 1) & 1;   // = 1
  hipLaunchKernelGGL(k_final, dim3(1), dim3(256), 0, stream,
                     Z, x64, p64, part[last], rho[last], mmdpart, out);
}

// Round 10
// 30715.939 us; speedup vs baseline: 2.5772x; 1.0128x over previous
//
#include <hip/hip_runtime.h>

#define NPTS 8192
#define N2 (NPTS * 2)
#define TPB 1024
#define NBLK 256           // 1 block per CU
#define IPB 32             // i-rows owned per block
#define IB 8               // i-rows per thread
#define NIG (IPB / IB)     // 4 i-groups
#define NJS 256            // j-slices
#define NCHK 8             // staging chunks
#define JCH (NPTS / NCHK)  // 1024 j per chunk
#define T_ITERS 1152
#define NUG 1.0e-4
#define LAM 1.0e-5

typedef float v2f __attribute__((ext_vector_type(2)));

#if __has_builtin(__builtin_amdgcn_exp2f)
#define EXP2F(x) __builtin_amdgcn_exp2f(x)
#else
#define EXP2F(x) __expf(0.6931471805599453f * (x))
#endif

// ---------------- setup ----------------
// u = x / sqrt(2 ln2)  =>  K_ij = 2^(u_i.w_j - n_i - n_j), w = 2u (SoA)
extern "C" __global__ void __launch_bounds__(256)
k_setup(const float* __restrict__ Xmu, const float* __restrict__ Yeta,
        const float* __restrict__ Ymu, const float* __restrict__ Z,
        float4* __restrict__ U4, float* __restrict__ WX, float* __restrict__ WY,
        float* __restrict__ WZ, float* __restrict__ WW, float* __restrict__ NS,
        float4* __restrict__ M4, float4* __restrict__ Y4,
        float4* __restrict__ SA1, float2* __restrict__ SB1,
        double* __restrict__ r64, double* __restrict__ p64,
        double* __restrict__ q64, double* __restrict__ x64,
        double* __restrict__ rrsetup)
{
  const float c2 = 0.84932180028802f;        // 1/sqrt(2 ln 2)
  int tid = threadIdx.x;
  int idx = blockIdx.x * 256 + tid;          // 0..16383 (64 blocks)
  int i = idx >> 1;
  float z = Z[idx];
  r64[idx] = (double)z;
  p64[idx] = 0.0;
  q64[idx] = 0.0;
  x64[idx] = 0.0;
  if ((idx & 1) == 0) {
    float a0 = Xmu[2 * i], a1 = Xmu[2 * i + 1];
    float e0 = Yeta[2 * i], e1 = Yeta[2 * i + 1];
    float m0 = Ymu[2 * i], m1 = Ymu[2 * i + 1];
    float z0 = Z[2 * i], z1 = Z[2 * i + 1];
    float u0 = c2 * a0, u1 = c2 * a1, u2 = c2 * e0, u3 = c2 * e1;
    float n = fmaf(u3, u3, fmaf(u2, u2, fmaf(u1, u1, u0 * u0)));
    U4[i] = make_float4(u0, u1, u2, u3);
    WX[i] = 2.f * u0; WY[i] = 2.f * u1; WZ[i] = 2.f * u2; WW[i] = 2.f * u3;
    NS[i] = n;
    M4[i] = make_float4(a0, a1, e0 + z0, e1 + z1);
    Y4[i] = make_float4(a0, a1, m0, m1);
    SA1[i] = make_float4(z0, z1, 0.f, 0.f);  // (r0,r1,p0,p1) at t=0
    SB1[i] = make_float2(0.f, 0.f);          // (q0,q1) at t=0
  }
  __shared__ double sd[256];
  sd[tid] = (double)z * (double)z;
  __syncthreads();
  for (int st = 128; st >= 2; st >>= 1) {
    if (tid < st) sd[tid] += sd[tid + st];
    __syncthreads();
  }
  if (tid < 2) rrsetup[blockIdx.x * 2 + tid] = sd[tid];   // 128 entries
}

// ---------------- MMD: three fused Gram sums ----------------
#define MTPB 256
#define MCH 1024
extern "C" __global__ void __launch_bounds__(MTPB)
k_mmd(const float4* __restrict__ M4, const float4* __restrict__ Y4,
      double* __restrict__ mmdpart)
{
  __shared__ float4 sM[MCH];
  __shared__ float4 sY[MCH];
  __shared__ double sred[MTPB];
  int tid = threadIdx.x;
  int blk = blockIdx.x;            // 256 = 32 itiles x 8 chunks
  int itile = blk >> 3;
  int ch = blk & 7;
  int j0 = ch * MCH;
  for (int u = tid; u < MCH; u += MTPB) {
    sM[u] = M4[j0 + u];
    sY[u] = Y4[j0 + u];
  }
  __syncthreads();
  int i = itile * MTPB + tid;
  float4 mi = M4[i];
  float4 yi = Y4[i];
  double szz = 0.0, szy = 0.0, syy = 0.0;
  for (int jj = 0; jj < MCH; ++jj) {
    float4 mj = sM[jj];
    float4 yj = sY[jj];
    float d0 = mi.x - mj.x, d1 = mi.y - mj.y;
    float a = fmaf(d1, d1, d0 * d0);
    float u0 = mi.z - mj.z, u1 = mi.w - mj.w;
    float v0 = mi.z - yj.z, v1 = mi.w - yj.w;
    float w0 = yi.z - yj.z, w1 = yi.w - yj.w;
    float dzz = fmaf(u0, u0, fmaf(u1, u1, a));
    float dzy = fmaf(v0, v0, fmaf(v1, v1, a));
    float dyy = fmaf(w0, w0, fmaf(w1, w1, a));
    szz += (double)__expf(-0.5f * dzz);
    szy += (double)__expf(-0.5f * dzy);
    syy += (double)__expf(-0.5f * dyy);
  }
  double v[3] = {szz, szy, syy};
  for (int k = 0; k < 3; ++k) {
    sred[tid] = v[k];
    __syncthreads();
    for (int st = MTPB >> 1; st >= 1; st >>= 1) {
      if (tid < st) sred[tid] += sred[tid + st];
      __syncthreads();
    }
    if (tid == 0) mmdpart[blk * 3 + k] = sred[0];
    __syncthreads();
  }
}

// ---------------- fused CG iteration, chunk-pipelined, packed f32 ----------------
extern "C" __global__ void __launch_bounds__(TPB, 4)
k_it(const float4* __restrict__ U4,
     const float* __restrict__ WX, const float* __restrict__ WY,
     const float* __restrict__ WZ, const float* __restrict__ WW,
     const float* __restrict__ NS,
     const float4* __restrict__ SAr, const float2* __restrict__ SBr,
     float4* __restrict__ SAw, float2* __restrict__ SBw,
     double* __restrict__ r64, double* __restrict__ p64,
     double* __restrict__ q64, double* __restrict__ x64,
     const double* __restrict__ partr, double* __restrict__ partw,
     const double* __restrict__ rhor, double* __restrict__ rhow,
     const double* __restrict__ rrsetup, int t)
{
  __shared__ float sp0[NPTS];                // pn col0 (SoA)       32 KB
  __shared__ float sp1[NPTS];                // pn col1             32 KB
  __shared__ double s1[TPB], s2[TPB], s3[TPB];                  // 24 KB
  __shared__ float qred[16][IB][2];          // per-wave partials   1 KB
  __shared__ double sc[4];                   // a0,a1,b0,b1

  int tid = threadIdx.x;
  int blk = blockIdx.x;

  // ---- issue chunk-0 staging loads before the scalar phase ----
  float4 sa_r = SAr[tid];                    // chunk 0: j = tid (1024 j)
  float2 sb_r = SBr[tid];

  // ---- scalar phase (redundant per block, deterministic) ----
  if (t == 0) {
    s1[tid] = (tid < 128) ? rrsetup[tid] : 0.0;
    __syncthreads();
    for (int st = 64; st >= 2; st >>= 1) {
      if (tid < st) s1[tid] += s1[tid + st];
      __syncthreads();
    }
    if (tid < 2) { rhow[tid] = s1[tid]; sc[tid] = 0.0; sc[2 + tid] = 0.0; }
    __syncthreads();
  } else {
    s1[tid] = (tid < 512) ? partr[tid] : 0.0;
    s2[tid] = (tid < 512) ? partr[1024 + tid] : 0.0;
    s3[tid] = (tid < 512) ? partr[2048 + tid] : 0.0;
    __syncthreads();
    for (int st = 512; st >= 2; st >>= 1) {
      if (tid < st) {
        s1[tid] += s1[tid + st];
        s2[tid] += s2[tid + st];
        s3[tid] += s3[tid + st];
      }
      __syncthreads();
    }
    if (tid < 2) {
      double rho_o = rhor[tid];
      double al = rho_o / s1[tid];
      double rho_n = fma(al, fma(al, s3[tid], -2.0 * s2[tid]), rho_o);
      rhow[tid] = rho_n;
      sc[tid] = al;
      sc[2 + tid] = rho_n / rho_o;
    }
    __syncthreads();
  }
  double da0 = sc[0], da1 = sc[1], db0 = sc[2], db1 = sc[3];
  float a0 = (float)da0, a1 = (float)da1, b0 = (float)db0, b1 = (float)db1;

  // ---- i-side registers ----
  int ig = tid >> 8;                         // 0..3
  int js = tid & (NJS - 1);                  // 0..255
  int i0 = blk * IPB + ig * IB;
  float4 ui[IB];
  float ni[IB];
#pragma unroll
  for (int k = 0; k < IB; ++k) { ui[k] = U4[i0 + k]; ni[k] = NS[i0 + k]; }

  v2f qa0[IB], qa1[IB];
#pragma unroll
  for (int k = 0; k < IB; ++k) { qa0[k] = (v2f)(0.f); qa1[k] = (v2f)(0.f); }

  // ---- chunk-pipelined: write chunk c, sync, compute c while loading c+1 ----
  sp0[tid] = fmaf(b0, sa_r.z, fmaf(-a0, sb_r.x, sa_r.x));
  sp1[tid] = fmaf(b1, sa_r.w, fmaf(-a1, sb_r.y, sa_r.y));
  __syncthreads();
  for (int c = 0; c < NCHK; ++c) {
    if (c + 1 < NCHK) {                      // prefetch next chunk into regs
      int j = (c + 1) * JCH + tid;
      sa_r = SAr[j];
      sb_r = SBr[j];
    }
    // compute chunk c: 2 jp-rounds x IB rows, packed over j-pairs
#pragma unroll
    for (int jj = 0; jj < 2; ++jj) {
      int jp = c * (JCH / 2) + jj * NJS + js;          // pair index
      v2f wx = ((const v2f*)WX)[jp];
      v2f wy = ((const v2f*)WY)[jp];
      v2f wz = ((const v2f*)WZ)[jp];
      v2f ww = ((const v2f*)WW)[jp];
      v2f nj = ((const v2f*)NS)[jp];
      v2f pn0 = ((const v2f*)sp0)[jp];
      v2f pn1 = ((const v2f*)sp1)[jp];
#pragma unroll
      for (int k = 0; k < IB; ++k) {
        v2f tt = -nj - ni[k];                // splat
        tt += ui[k].x * wx;                  // contracts to v_pk_fma_f32
        tt += ui[k].y * wy;
        tt += ui[k].z * wz;
        tt += ui[k].w * ww;
        v2f e;
        e.x = EXP2F(tt.x);
        e.y = EXP2F(tt.y);
        qa0[k] += e * pn0;
        qa1[k] += e * pn1;
      }
    }
    if (c + 1 < NCHK) {                      // disjoint sp region: no WAR
      int j = (c + 1) * JCH + tid;
      sp0[j] = fmaf(b0, sa_r.z, fmaf(-a0, sb_r.x, sa_r.x));
      sp1[j] = fmaf(b1, sa_r.w, fmaf(-a1, sb_r.y, sa_r.y));
      __syncthreads();
    }
  }

  // ---- reduce: fold pair, wave shuffle, cross-wave via LDS ----
  float q0s[IB], q1s[IB];
#pragma unroll
  for (int k = 0; k < IB; ++k) {
    q0s[k] = qa0[k].x + qa0[k].y;
    q1s[k] = qa1[k].x + qa1[k].y;
#pragma unroll
    for (int d = 32; d >= 1; d >>= 1) {
      q0s[k] += __shfl_down(q0s[k], (unsigned)d, 64);
      q1s[k] += __shfl_down(q1s[k], (unsigned)d, 64);
    }
  }
  {
    int lane = tid & 63, wv = tid >> 6;      // 16 waves; ig = wv>>2
    if (lane == 0) {
#pragma unroll
      for (int k = 0; k < IB; ++k) {
        qred[wv][k][0] = q0s[k];
        qred[wv][k][1] = q1s[k];
      }
    }
  }
  __syncthreads();

  // ---- epilogue: owner rows (tid<64), f64 recurrence ----
  double pqv = 0.0, rqv = 0.0, qqv = 0.0;
  if (tid < 2 * IPB) {
    int io = tid >> 1, col = tid & 1;
    int oidx = blk * (2 * IPB) + tid;
    int wb = (io >> 3) * 4, k = io & 7;
    double qg = (double)qred[wb][k][col] + (double)qred[wb + 1][k][col]
              + (double)qred[wb + 2][k][col] + (double)qred[wb + 3][k][col];
    double al = col ? da1 : da0;
    double be = col ? db1 : db0;
    double rold = r64[oidx], pold = p64[oidx], qold = q64[oidx];
    double rn = fma(-al, qold, rold);        // r_t
    double pn = fma(be, pold, rn);           // p_t
    double xn = fma(al, pold, x64[oidx]);    // x_t
    double qn = fma((double)NUG, pn, qg);    // q_t
    r64[oidx] = rn; p64[oidx] = pn; q64[oidx] = qn; x64[oidx] = xn;
    int i = blk * IPB + io;
    float* SAf = (float*)SAw;
    float* SBf = (float*)SBw;
    SAf[i * 4 + col] = (float)rn;
    SAf[i * 4 + 2 + col] = (float)pn;
    SBf[i * 2 + col] = (float)qn;
    pqv = pn * qn;
    rqv = rn * qn;
    qqv = qn * qn;
  }
  s1[tid] = pqv; s2[tid] = rqv; s3[tid] = qqv;
  __syncthreads();
  for (int st = IPB; st >= 2; st >>= 1) {
    if (tid < st) {
      s1[tid] += s1[tid + st];
      s2[tid] += s2[tid + st];
      s3[tid] += s3[tid + st];
    }
    __syncthreads();
  }
  if (tid < 2) {
    partw[blk * 2 + tid] = s1[tid];
    partw[1024 + blk * 2 + tid] = s2[tid];
    partw[2048 + blk * 2 + tid] = s3[tid];
  }
}

// ---------------- final: last x half-step + combine ----------------
extern "C" __global__ void __launch_bounds__(256)
k_final(const float* __restrict__ Z, const double* __restrict__ x64,
        const double* __restrict__ p64, const double* __restrict__ part_last,
        const double* __restrict__ rho_last, const double* __restrict__ mmdpart,
        float* __restrict__ out)
{
  __shared__ double s1[256];
  __shared__ double sc2[2];
  int tid = threadIdx.x;
  s1[tid] = part_last[tid] + part_last[tid + 256];
  __syncthreads();
  for (int st = 128; st >= 2; st >>= 1) {
    if (tid < st) s1[tid] += s1[tid + st];
    __syncthreads();
  }
  if (tid < 2) sc2[tid] = rho_last[tid] / s1[tid];
  __syncthreads();
  double al = sc2[tid & 1];
  double zx = 0.0;
  for (int idx = tid; idx < N2; idx += 256)   // stride even: parity fixed
    zx += (double)Z[idx] * fma(al, p64[idx], x64[idx]);
  double acc[4];
  acc[0] = zx;
  acc[1] = mmdpart[tid * 3 + 0];
  acc[2] = mmdpart[tid * 3 + 1];
  acc[3] = mmdpart[tid * 3 + 2];
  double tot[4];
  for (int k = 0; k < 4; ++k) {
    s1[tid] = acc[k];
    __syncthreads();
    for (int st = 128; st >= 1; st >>= 1) {
      if (tid < st) s1[tid] += s1[tid + st];
      __syncthreads();
    }
    tot[k] = s1[0];
    __syncthreads();
  }
  if (tid == 0) {
    double nn = (double)NPTS * (double)NPTS;
    double mmd = (tot[1] - 2.0 * tot[2] + tot[3]) / nn;
    out[0] = (float)(mmd + LAM * tot[0]);
  }
}

extern "C" void kernel_launch(void* const* d_in, const int* in_sizes, int n_in,
                              void* d_out, int out_size, void* d_ws, size_t ws_size,
                              hipStream_t stream)
{
  (void)in_sizes; (void)n_in; (void)out_size; (void)ws_size;
  const float* Xmu  = (const float*)d_in[0];
  const float* Yeta = (const float*)d_in[1];
  const float* Ymu  = (const float*)d_in[2];
  const float* Z    = (const float*)d_in[3];
  float* out = (float*)d_out;

  char* w = (char*)d_ws;
  float4* U4      = (float4*)(w);                      // 128K
  float*  WX      = (float*)(w + (128 << 10));         // 32K
  float*  WY      = (float*)(w + (160 << 10));         // 32K
  float*  WZ      = (float*)(w + (192 << 10));         // 32K
  float*  WW      = (float*)(w + (224 << 10));         // 32K
  float*  NS      = (float*)(w + (256 << 10));         // 32K
  float4* M4      = (float4*)(w + (288 << 10));        // 128K
  float4* Y4      = (float4*)(w + (416 << 10));        // 128K
  float4* SA[2]   = { (float4*)(w + (544 << 10)), (float4*)(w + (672 << 10)) };
  float2* SB[2]   = { (float2*)(w + (800 << 10)), (float2*)(w + (864 << 10)) };
  double* r64     = (double*)(w + (928 << 10));        // 128K
  double* p64     = (double*)(w + (1056 << 10));       // 128K
  double* q64     = (double*)(w + (1184 << 10));       // 128K
  double* x64     = (double*)(w + (1312 << 10));       // 128K
  double* part[2] = { (double*)(w + (1440 << 10)), (double*)(w + (1464 << 10)) };
  double* rho[2]  = { (double*)(w + (1488 << 10)), (double*)(w + (1488 << 10) + 64) };
  double* rrsetup = (double*)(w + (1489 << 10));       // 1K
  double* mmdpart = (double*)(w + (1490 << 10));       // 6K

  hipLaunchKernelGGL(k_setup, dim3(64), dim3(256), 0, stream,
                     Xmu, Yeta, Ymu, Z, U4, WX, WY, WZ, WW, NS, M4, Y4,
                     SA[1], SB[1], r64, p64, q64, x64, rrsetup);
  hipLaunchKernelGGL(k_mmd, dim3(256), dim3(MTPB), 0, stream, M4, Y4, mmdpart);

  for (int t = 0; t < T_ITERS; ++t) {
    int cur = t & 1, prv = cur ^ 1;
    hipLaunchKernelGGL(k_it, dim3(NBLK), dim3(TPB), 0, stream,
                       U4, WX, WY, WZ, WW, NS, SA[prv], SB[prv], SA[cur], SB[cur],
                       r64, p64, q64, x64,
                       part[prv], part[cur], rho[prv], rho[cur], rrsetup, t);
  }
  int last = (T_ITERS - 1) & 1;   // = 1
  hipLaunchKernelGGL(k_final, dim3(1), dim3(256), 0, stream,
                     Z, x64, p64, part[last], rho[last], mmdpart, out);
}